// Round 1
// baseline (2016.462 us; speedup 1.0000x reference)
//
#include <hip/hip_runtime.h>
#include <hip/hip_bf16.h>

#define B_     8
#define N_     1024
#define DIM_   1024
#define HEADS_ 16
#define DH_    64
#define INNER_ 1024
#define NKEY_  1025
#define ROWS_  8192
#define EPS_   1e-5f
#define QK_SCALE_ 0.125f   // DIM_HEAD^-0.5 == SCALE*ALPHA folded

typedef unsigned short u16;

__device__ __forceinline__ float bf2f(u16 u) {
    unsigned int x = ((unsigned int)u) << 16;
    return __uint_as_float(x);
}
__device__ __forceinline__ u16 f2bf(float f) {
    unsigned int x = __float_as_uint(f);
    x += 0x7FFFu + ((x >> 16) & 1u);   // RNE
    return (u16)(x >> 16);
}

// ---------------- mask representation handling ----------------
// jax bool mask may arrive as 1-byte bool, int32, or float32. Detect from data.
__global__ void detect_mask(const unsigned int* __restrict__ m, int* __restrict__ flag) {
    if (threadIdx.x == 0 && blockIdx.x == 0) {
        int f = 0;  // 0=int32, 1=bytes(bool), 2=float32
        for (int i = 0; i < 64; ++i) {
            unsigned int w = m[i];
            if (w == 0x3F800000u) { f = 2; break; }
            if (w > 1u) f = 1;
        }
        *flag = f;
    }
}

__global__ void canon_mask(const void* __restrict__ m, const int* __restrict__ flag,
                           unsigned char* __restrict__ out, int n) {
    int i = blockIdx.x * blockDim.x + threadIdx.x;
    if (i >= n) return;
    int f = *flag;
    unsigned char r;
    if (f == 0)      r = (unsigned char)(((const int*)m)[i] != 0);
    else if (f == 1) r = (unsigned char)(((const unsigned char*)m)[i] != 0);
    else             r = (unsigned char)(((const float*)m)[i] != 0.0f);
    out[i] = r;
}

// ---------------- layernorm over rows of 1024 ----------------
template<bool BF16OUT>
__global__ __launch_bounds__(256)
void ln_rows(const float* __restrict__ x, const float* __restrict__ g,
             void* __restrict__ outv) {
    int row = blockIdx.x;
    int t = threadIdx.x;
    const float* xr = x + (size_t)row * DIM_;
    float4 v = ((const float4*)xr)[t];
    float s  = v.x + v.y + v.z + v.w;
    float ss = v.x*v.x + v.y*v.y + v.z*v.z + v.w*v.w;
#pragma unroll
    for (int off = 32; off > 0; off >>= 1) {
        s  += __shfl_down(s,  off, 64);
        ss += __shfl_down(ss, off, 64);
    }
    __shared__ float red[10];
    int wid = t >> 6, lane = t & 63;
    if (lane == 0) { red[wid] = s; red[4 + wid] = ss; }
    __syncthreads();
    if (t == 0) {
        float S  = red[0] + red[1] + red[2] + red[3];
        float SS = red[4] + red[5] + red[6] + red[7];
        float mean = S * (1.0f / DIM_);
        float var  = SS * (1.0f / DIM_) - mean * mean;
        red[8] = mean;
        red[9] = rsqrtf(var + EPS_);
    }
    __syncthreads();
    float mean = red[8], rs = red[9];
    float4 gv = ((const float4*)g)[t];
    float o0 = (v.x - mean) * rs * gv.x;
    float o1 = (v.y - mean) * rs * gv.y;
    float o2 = (v.z - mean) * rs * gv.z;
    float o3 = (v.w - mean) * rs * gv.w;
    if constexpr (BF16OUT) {
        ushort4 u; u.x = f2bf(o0); u.y = f2bf(o1); u.z = f2bf(o2); u.w = f2bf(o3);
        ((ushort4*)((u16*)outv + (size_t)row * DIM_))[t] = u;
    } else {
        float4 u; u.x = o0; u.y = o1; u.z = o2; u.w = o3;
        ((float4*)((float*)outv + (size_t)row * DIM_))[t] = u;
    }
}

// ---------------- C = A @ B^T (A: MxK bf16 or f32, B: NxK f32) ----------------
template<bool AF32, bool BF16OUT>
__global__ __launch_bounds__(256)
void gemm_nt(const void* __restrict__ Av, const float* __restrict__ Bw,
             void* __restrict__ Cv, int M, int Nn, int K, float scale) {
    __shared__ float As[64][33];
    __shared__ float Bs[64][33];
    int m0 = blockIdx.y * 64, n0 = blockIdx.x * 64;
    int t  = threadIdx.x;
    int tx = t & 15, ty = t >> 4;
    int srow = t >> 2;
    int skk  = (t & 3) * 8;
    float acc[4][4] = {};
    for (int k0 = 0; k0 < K; k0 += 32) {
        if constexpr (AF32) {
            const float* ap = (const float*)Av + (size_t)(m0 + srow) * K + k0 + skk;
            float4 f0 = ((const float4*)ap)[0];
            float4 f1 = ((const float4*)ap)[1];
            As[srow][skk+0]=f0.x; As[srow][skk+1]=f0.y; As[srow][skk+2]=f0.z; As[srow][skk+3]=f0.w;
            As[srow][skk+4]=f1.x; As[srow][skk+5]=f1.y; As[srow][skk+6]=f1.z; As[srow][skk+7]=f1.w;
        } else {
            const u16* ap = (const u16*)Av + (size_t)(m0 + srow) * K + k0 + skk;
            ushort4 u0 = ((const ushort4*)ap)[0];
            ushort4 u1 = ((const ushort4*)ap)[1];
            As[srow][skk+0]=bf2f(u0.x); As[srow][skk+1]=bf2f(u0.y);
            As[srow][skk+2]=bf2f(u0.z); As[srow][skk+3]=bf2f(u0.w);
            As[srow][skk+4]=bf2f(u1.x); As[srow][skk+5]=bf2f(u1.y);
            As[srow][skk+6]=bf2f(u1.z); As[srow][skk+7]=bf2f(u1.w);
        }
        {
            const float* bp = Bw + (size_t)(n0 + srow) * K + k0 + skk;
            float4 f0 = ((const float4*)bp)[0];
            float4 f1 = ((const float4*)bp)[1];
            Bs[srow][skk+0]=f0.x; Bs[srow][skk+1]=f0.y; Bs[srow][skk+2]=f0.z; Bs[srow][skk+3]=f0.w;
            Bs[srow][skk+4]=f1.x; Bs[srow][skk+5]=f1.y; Bs[srow][skk+6]=f1.z; Bs[srow][skk+7]=f1.w;
        }
        __syncthreads();
#pragma unroll
        for (int kk = 0; kk < 32; ++kk) {
            float a0 = As[ty*4+0][kk], a1 = As[ty*4+1][kk];
            float a2 = As[ty*4+2][kk], a3 = As[ty*4+3][kk];
            float b0 = Bs[tx*4+0][kk], b1 = Bs[tx*4+1][kk];
            float b2 = Bs[tx*4+2][kk], b3 = Bs[tx*4+3][kk];
            acc[0][0] += a0*b0; acc[0][1] += a0*b1; acc[0][2] += a0*b2; acc[0][3] += a0*b3;
            acc[1][0] += a1*b0; acc[1][1] += a1*b1; acc[1][2] += a1*b2; acc[1][3] += a1*b3;
            acc[2][0] += a2*b0; acc[2][1] += a2*b1; acc[2][2] += a2*b2; acc[2][3] += a2*b3;
            acc[3][0] += a3*b0; acc[3][1] += a3*b1; acc[3][2] += a3*b2; acc[3][3] += a3*b3;
        }
        __syncthreads();
    }
#pragma unroll
    for (int i2 = 0; i2 < 4; ++i2) {
        size_t r = (size_t)(m0 + ty*4 + i2);
        int c = n0 + tx*4;
        if constexpr (BF16OUT) {
            ushort4 u;
            u.x = f2bf(acc[i2][0]*scale); u.y = f2bf(acc[i2][1]*scale);
            u.z = f2bf(acc[i2][2]*scale); u.w = f2bf(acc[i2][3]*scale);
            *(ushort4*)((u16*)Cv + r*Nn + c) = u;
        } else {
            float4 u;
            u.x = acc[i2][0]*scale; u.y = acc[i2][1]*scale;
            u.z = acc[i2][2]*scale; u.w = acc[i2][3]*scale;
            *(float4*)((float*)Cv + r*Nn + c) = u;
        }
    }
}

// ---------------- build padded K/V with null token at j=0 ----------------
__global__ void build_kv(const float* __restrict__ kv, const float* __restrict__ null_kv,
                         float* __restrict__ Kp, float* __restrict__ Vp) {
    int tid = blockIdx.x * blockDim.x + threadIdx.x;
    if (tid >= B_ * NKEY_ * DH_) return;
    int d = tid & 63;
    int j = (tid >> 6) % NKEY_;
    int b = tid / (64 * NKEY_);
    float kvl, vvl;
    if (j == 0) { kvl = null_kv[d]; vvl = null_kv[64 + d]; }
    else {
        const float* row = kv + (size_t)(b * N_ + (j - 1)) * 128;
        kvl = row[d]; vvl = row[64 + d];
    }
    size_t o = (size_t)(b * NKEY_ + j) * DH_ + d;
    Kp[o] = kvl; Vp[o] = vvl;
}

// ---------------- flash attention: 1 wave per 64-query tile ----------------
__global__ __launch_bounds__(64)
void attn_kernel(const u16* __restrict__ Q, const float* __restrict__ Kp,
                 const float* __restrict__ Vp, const unsigned char* __restrict__ mask8,
                 u16* __restrict__ Out) {
    int t = threadIdx.x;
    int qtile = blockIdx.x;           // 0..15
    int bh = blockIdx.y;              // 0..127
    int b = bh >> 4, h = bh & 15;
    int i = qtile * 64 + t;           // this lane's query row

    float q[64];
    const u16* qp = Q + (size_t)(b * N_ + i) * INNER_ + h * DH_;
#pragma unroll
    for (int d4 = 0; d4 < 16; ++d4) {
        ushort4 u = ((const ushort4*)qp)[d4];
        q[d4*4+0] = bf2f(u.x); q[d4*4+1] = bf2f(u.y);
        q[d4*4+2] = bf2f(u.z); q[d4*4+3] = bf2f(u.w);
    }
    float o[64];
#pragma unroll
    for (int d = 0; d < 64; ++d) o[d] = 0.f;
    float m_run = -3.0e38f, l_run = 0.f;

    __shared__ float ks[64][64];
    __shared__ float vs[64][64];
    __shared__ unsigned char msk[64];

    int ntile = qtile + 2;            // key tiles to visit (incl. partial causal tile)
    for (int kt = 0; kt < ntile; ++kt) {
        int j0 = kt * 64;
        __syncthreads();
        // stage 64 keys + values (f32), coalesced float4
#pragma unroll
        for (int s = 0; s < 16; ++s) {
            int e  = s * 64 + t;
            int r  = e >> 4;
            int c4 = e & 15;
            int j = j0 + r;
            float4 kv4 = {0,0,0,0}, vv4 = {0,0,0,0};
            if (j < NKEY_) {
                size_t base = (size_t)(b * NKEY_ + j) * DH_;
                kv4 = ((const float4*)(Kp + base))[c4];
                vv4 = ((const float4*)(Vp + base))[c4];
            }
            ((float4*)&ks[r][0])[c4] = kv4;
            ((float4*)&vs[r][0])[c4] = vv4;
        }
        {
            int j = j0 + t;
            msk[t] = (j < NKEY_) && (j == 0 || mask8[b * N_ + j - 1] != 0);
        }
        __syncthreads();

        int jmax = i + 1 - j0; if (jmax > 63) jmax = 63;
        for (int jj = 0; jj <= jmax; ++jj) {
            if (!msk[jj]) continue;   // wave-uniform (mask depends on b,j only)
            float s0=0,s1=0,s2=0,s3=0;
#pragma unroll
            for (int d = 0; d < 64; d += 4) {
                s0 += q[d+0] * ks[jj][d+0];
                s1 += q[d+1] * ks[jj][d+1];
                s2 += q[d+2] * ks[jj][d+2];
                s3 += q[d+3] * ks[jj][d+3];
            }
            float sc = (s0+s1) + (s2+s3);   // logit (scale folded into q)
            float mn = fmaxf(m_run, sc);
            if (__any(sc > m_run)) {
                float c = __expf(m_run - mn);
                l_run *= c;
#pragma unroll
                for (int d = 0; d < 64; ++d) o[d] *= c;
                m_run = mn;
            }
            float p = __expf(sc - m_run);
            l_run += p;
#pragma unroll
            for (int d = 0; d < 64; ++d) o[d] += p * vs[jj][d];
        }
    }

    float inv = 1.0f / l_run;
    u16* op = Out + (size_t)(b * N_ + i) * INNER_ + h * DH_;
#pragma unroll
    for (int d4 = 0; d4 < 16; ++d4) {
        ushort4 u;
        u.x = f2bf(o[d4*4+0] * inv); u.y = f2bf(o[d4*4+1] * inv);
        u.z = f2bf(o[d4*4+2] * inv); u.w = f2bf(o[d4*4+3] * inv);
        ((ushort4*)op)[d4] = u;
    }
}

// ---------------- launch ----------------
extern "C" void kernel_launch(void* const* d_in, const int* in_sizes, int n_in,
                              void* d_out, int out_size, void* d_ws, size_t ws_size,
                              hipStream_t stream) {
    const float* x       = (const float*)d_in[0];
    const void*  maskraw = d_in[1];
    const float* g_in    = (const float*)d_in[2];
    const float* Wq      = (const float*)d_in[3];
    const float* Wkv     = (const float*)d_in[4];
    const float* null_kv = (const float*)d_in[5];
    const float* Wo      = (const float*)d_in[6];
    const float* g_out   = (const float*)d_in[7];
    float* out = (float*)d_out;

    char* ws = (char*)d_ws;
    size_t off = 0;
    auto alloc = [&](size_t bytes) {
        void* p = ws + off;
        off += (bytes + 255) & ~(size_t)255;
        return p;
    };
    int* flag            = (int*)alloc(4);
    unsigned char* mask8 = (unsigned char*)alloc((size_t)B_ * N_);
    u16* xn              = (u16*)alloc((size_t)ROWS_ * DIM_ * 2);
    u16* q               = (u16*)alloc((size_t)ROWS_ * INNER_ * 2);
    float* kv            = (float*)alloc((size_t)ROWS_ * 128 * 4);
    float* Kp            = (float*)alloc((size_t)B_ * NKEY_ * DH_ * 4);
    float* Vp            = (float*)alloc((size_t)B_ * NKEY_ * DH_ * 4);
    u16* attn            = (u16*)alloc((size_t)ROWS_ * INNER_ * 2);
    float* proj          = (float*)alloc((size_t)ROWS_ * DIM_ * 4);

    detect_mask<<<1, 64, 0, stream>>>((const unsigned int*)maskraw, flag);
    canon_mask<<<(B_*N_ + 255)/256, 256, 0, stream>>>(maskraw, flag, mask8, B_*N_);

    ln_rows<true><<<ROWS_, 256, 0, stream>>>(x, g_in, xn);

    // Q = (xn @ Wq^T) * 0.125  -> bf16
    gemm_nt<false, true><<<dim3(INNER_/64, ROWS_/64), 256, 0, stream>>>(
        xn, Wq, q, ROWS_, INNER_, DIM_, QK_SCALE_);

    // KV = x @ Wkv^T (context = pre-norm x) -> f32
    gemm_nt<true, false><<<dim3(128/64, ROWS_/64), 256, 0, stream>>>(
        x, Wkv, kv, ROWS_, 128, DIM_, 1.0f);

    build_kv<<<(B_*NKEY_*DH_ + 255)/256, 256, 0, stream>>>(kv, null_kv, Kp, Vp);

    attn_kernel<<<dim3(N_/64, B_*HEADS_), 64, 0, stream>>>(q, Kp, Vp, mask8, attn);

    // proj = attn @ Wo^T -> f32
    gemm_nt<false, false><<<dim3(DIM_/64, ROWS_/64), 256, 0, stream>>>(
        attn, Wo, proj, ROWS_, DIM_, INNER_, 1.0f);

    ln_rows<false><<<ROWS_, 256, 0, stream>>>(proj, g_out, out);
}

// Round 2
// 333.252 us; speedup vs baseline: 6.0509x; 6.0509x over previous
//
#include <hip/hip_runtime.h>
#include <hip/hip_bf16.h>

#define B_     8
#define N_     1024
#define DIM_   1024
#define HEADS_ 16
#define DH_    64
#define INNER_ 1024
#define NKEY_  1025
#define NKP_   1056      // keys padded to multiple of 32
#define ROWS_  8192
#define EPS_   1e-5f
#define QK_SCALE_ 0.125f   // DIM_HEAD^-0.5; ALPHA/pb-relax cancels in softmax

typedef unsigned short u16;
typedef unsigned char  u8;
typedef __attribute__((ext_vector_type(8))) short short8;   // 8 bf16 = 4 VGPR
typedef __attribute__((ext_vector_type(4))) float f32x4;

__device__ __forceinline__ float bf2f(u16 u) {
    unsigned int x = ((unsigned int)u) << 16;
    return __uint_as_float(x);
}
__device__ __forceinline__ u16 f2bf(float f) {
    unsigned int x = __float_as_uint(f);
    x += 0x7FFFu + ((x >> 16) & 1u);   // RNE
    return (u16)(x >> 16);
}

#define MFMA16(a, b, c) __builtin_amdgcn_mfma_f32_16x16x32_bf16((a), (b), (c), 0, 0, 0)

__device__ __forceinline__ void gload16(const void* g, void* l) {
    __builtin_amdgcn_global_load_lds(
        (const __attribute__((address_space(1))) unsigned int*)g,
        (__attribute__((address_space(3))) unsigned int*)l, 16, 0, 0);
}

// ---------------- mask representation handling ----------------
__global__ void detect_mask(const unsigned int* __restrict__ m, int* __restrict__ flag) {
    if (threadIdx.x == 0 && blockIdx.x == 0) {
        int f = 0;  // 0=int32, 1=bytes(bool), 2=float32
        for (int i = 0; i < 64; ++i) {
            unsigned int w = m[i];
            if (w == 0x3F800000u) { f = 2; break; }
            if (w > 1u) f = 1;
        }
        *flag = f;
    }
}

__global__ void canon_mask(const void* __restrict__ m, const int* __restrict__ flag,
                           u8* __restrict__ out, int n) {
    int i = blockIdx.x * blockDim.x + threadIdx.x;
    if (i >= n) return;
    int f = *flag;
    u8 r;
    if (f == 0)      r = (u8)(((const int*)m)[i] != 0);
    else if (f == 1) r = (u8)(((const u8*)m)[i] != 0);
    else             r = (u8)(((const float*)m)[i] != 0.0f);
    out[i] = r;
}

// ---------------- f32 -> bf16 convert ----------------
__global__ void f32_to_bf16(const float* __restrict__ in, u16* __restrict__ out, int n4) {
    int i = blockIdx.x * blockDim.x + threadIdx.x;
    if (i >= n4) return;
    float4 v = ((const float4*)in)[i];
    ushort4 u; u.x = f2bf(v.x); u.y = f2bf(v.y); u.z = f2bf(v.z); u.w = f2bf(v.w);
    ((ushort4*)out)[i] = u;
}

// ---------------- layernorm over rows of 1024 ----------------
// MODE 0: f32 in -> bf16 LN out + bf16 raw copy; MODE 1: bf16 in -> f32 LN out
template<int MODE>
__global__ __launch_bounds__(256)
void ln_rows(const void* __restrict__ xv, const float* __restrict__ g,
             void* __restrict__ outv, u16* __restrict__ raw16) {
    int row = blockIdx.x;
    int t = threadIdx.x;
    float v0, v1, v2, v3;
    if constexpr (MODE == 0) {
        float4 v = ((const float4*)((const float*)xv + (size_t)row * DIM_))[t];
        v0 = v.x; v1 = v.y; v2 = v.z; v3 = v.w;
    } else {
        ushort4 u = ((const ushort4*)((const u16*)xv + (size_t)row * DIM_))[t];
        v0 = bf2f(u.x); v1 = bf2f(u.y); v2 = bf2f(u.z); v3 = bf2f(u.w);
    }
    float s  = v0 + v1 + v2 + v3;
    float ss = v0*v0 + v1*v1 + v2*v2 + v3*v3;
#pragma unroll
    for (int off = 32; off > 0; off >>= 1) {
        s  += __shfl_down(s,  off, 64);
        ss += __shfl_down(ss, off, 64);
    }
    __shared__ float red[10];
    int wid = t >> 6, lane = t & 63;
    if (lane == 0) { red[wid] = s; red[4 + wid] = ss; }
    __syncthreads();
    if (t == 0) {
        float S  = red[0] + red[1] + red[2] + red[3];
        float SS = red[4] + red[5] + red[6] + red[7];
        float mean = S * (1.0f / DIM_);
        float var  = SS * (1.0f / DIM_) - mean * mean;
        red[8] = mean;
        red[9] = rsqrtf(var + EPS_);
    }
    __syncthreads();
    float mean = red[8], rs = red[9];
    float4 gv = ((const float4*)g)[t];
    float o0 = (v0 - mean) * rs * gv.x;
    float o1 = (v1 - mean) * rs * gv.y;
    float o2 = (v2 - mean) * rs * gv.z;
    float o3 = (v3 - mean) * rs * gv.w;
    if constexpr (MODE == 0) {
        ushort4 u; u.x = f2bf(o0); u.y = f2bf(o1); u.z = f2bf(o2); u.w = f2bf(o3);
        ((ushort4*)((u16*)outv + (size_t)row * DIM_))[t] = u;
        ushort4 rw; rw.x = f2bf(v0); rw.y = f2bf(v1); rw.z = f2bf(v2); rw.w = f2bf(v3);
        ((ushort4*)(raw16 + (size_t)row * DIM_))[t] = rw;
    } else {
        float4 u; u.x = o0; u.y = o1; u.z = o2; u.w = o3;
        ((float4*)((float*)outv + (size_t)row * DIM_))[t] = u;
    }
}

// ---------------- MFMA GEMM: C = A(bf16 MxK) @ Bt(bf16 NxK)^T ----------------
// m97 structure: 128x128 tile, BK=32, 4 waves, global_load_lds width 16.
template<bool BF16OUT>
__global__ __launch_bounds__(256)
void gemm_mfma(const u16* __restrict__ A, const u16* __restrict__ Bt,
               void* __restrict__ Cv, int M, int Nn, int K, float scale) {
    __shared__ u16 As[128 * 32];
    __shared__ u16 Bs[128 * 32];
    const int t = threadIdx.x;
    const int w = t >> 6, l = t & 63;
    const int col = l & 15, rg = l >> 4;
    const int wm = (w >> 1) * 64, wn = (w & 1) * 64;
    const int m0 = blockIdx.y * 128, n0 = blockIdx.x * 128;
    const int slr = l >> 2;          // staging row within 16-row block
    const int slc = (l & 3) * 8;     // staging col (elements)
    f32x4 acc[4][4];
#pragma unroll
    for (int i = 0; i < 4; ++i)
#pragma unroll
        for (int j = 0; j < 4; ++j) acc[i][j] = f32x4{0.f, 0.f, 0.f, 0.f};

    const u16* Abase = A  + (size_t)m0 * K;
    const u16* Bbase = Bt + (size_t)n0 * K;
    for (int k0 = 0; k0 < K; k0 += 32) {
        __syncthreads();
#pragma unroll
        for (int p = 0; p < 2; ++p) {
            int rb = w * 2 + p;      // 0..7 : 16-row block
            gload16(Abase + (size_t)(rb * 16 + slr) * K + k0 + slc, &As[rb * 512]);
            gload16(Bbase + (size_t)(rb * 16 + slr) * K + k0 + slc, &Bs[rb * 512]);
        }
        __syncthreads();             // drains vmcnt(0): LDS tiles ready
        short8 af[4], bf4[4];
#pragma unroll
        for (int mi = 0; mi < 4; ++mi)
            af[mi] = *(const short8*)&As[(wm + mi * 16 + col) * 32 + rg * 8];
#pragma unroll
        for (int ni = 0; ni < 4; ++ni)
            bf4[ni] = *(const short8*)&Bs[(wn + ni * 16 + col) * 32 + rg * 8];
#pragma unroll
        for (int mi = 0; mi < 4; ++mi)
#pragma unroll
            for (int ni = 0; ni < 4; ++ni)
                acc[mi][ni] = MFMA16(af[mi], bf4[ni], acc[mi][ni]);
    }
#pragma unroll
    for (int mi = 0; mi < 4; ++mi)
#pragma unroll
        for (int ni = 0; ni < 4; ++ni)
#pragma unroll
            for (int r = 0; r < 4; ++r) {
                int row = m0 + wm + mi * 16 + rg * 4 + r;
                int c   = n0 + wn + ni * 16 + col;
                float vv = acc[mi][ni][r] * scale;
                if constexpr (BF16OUT) ((u16*)Cv)[(size_t)row * Nn + c] = f2bf(vv);
                else                   ((float*)Cv)[(size_t)row * Nn + c] = vv;
            }
}

// ---------------- build K (row-major) and V^T (d-major), bf16, padded ----------------
__global__ __launch_bounds__(256)
void build_kv(const float* __restrict__ kv, const float* __restrict__ nullkv,
              u16* __restrict__ Kb, u16* __restrict__ Vt) {
    int jt = blockIdx.x;     // 17 tiles of 64 j (covers 0..1087, guarded to NKP_)
    int b  = blockIdx.y;
    __shared__ u16 vs[64][66];   // 66: word-stride 33 -> conflict-free transpose
    int t = threadIdx.x;
#pragma unroll
    for (int p = 0; p < 16; ++p) {
        int idx = p * 256 + t;       // 64 j x 64 d
        int jl = idx >> 6, d = idx & 63;
        int j = jt * 64 + jl;
        float kf = 0.f, vf = 0.f;
        if (j == 0) { kf = nullkv[d]; vf = nullkv[64 + d]; }
        else if (j <= N_) {
            const float* row = kv + (size_t)(b * N_ + j - 1) * 128;
            kf = row[d]; vf = row[64 + d];
        }
        if (j < NKP_) Kb[((size_t)b * NKP_ + j) * 64 + d] = f2bf(kf);
        vs[d][jl] = f2bf(vf);
    }
    __syncthreads();
#pragma unroll
    for (int p = 0; p < 16; ++p) {
        int idx = p * 256 + t;
        int d = idx >> 6, jl = idx & 63;
        int j = jt * 64 + jl;
        if (j < NKP_) Vt[((size_t)b * 64 + d) * NKP_ + j] = vs[d][jl];
    }
}

// ---------------- MFMA flash attention ----------------
// 4 waves/block, wave = 16 queries of one (b,h). KVBLK=32.
// K/V read directly from global (L2-resident, shared by 16 heads).
__global__ __launch_bounds__(256)
void attn_mfma(const u16* __restrict__ Q, const u16* __restrict__ Kb,
               const u16* __restrict__ Vt, const u8* __restrict__ mask8,
               u16* __restrict__ Out) {
    __shared__ u16 plds[4][16][40];   // row stride 80B: 16B-aligned, ~2-way banks
    const int t = threadIdx.x;
    const int w = t >> 6, l = t & 63;
    const int col = l & 15, rg = l >> 4;
    const int qt = blockIdx.x * 4 + w;
    const int i0 = qt * 16;
    const int b = blockIdx.y >> 4, h = blockIdx.y & 15;

    short8 aq0, aq1;
    {
        const u16* qb = Q + (size_t)(b * N_ + i0 + col) * INNER_ + h * DH_ + rg * 8;
        aq0 = *(const short8*)qb;
        aq1 = *(const short8*)(qb + 32);
    }
    f32x4 o0 = {0,0,0,0}, o1 = {0,0,0,0}, o2 = {0,0,0,0}, o3 = {0,0,0,0};
    float mr[4] = {-3e38f, -3e38f, -3e38f, -3e38f};
    float lr[4] = {0.f, 0.f, 0.f, 0.f};

    const int nkt = (i0 + 16) / 32 + 1;
    for (int kt = 0; kt < nkt; ++kt) {
        const int k0 = kt * 32;
        f32x4 s0 = {0,0,0,0}, s1 = {0,0,0,0};
        {
            const u16* kb = Kb + ((size_t)b * NKP_ + k0 + col) * 64 + rg * 8;
            short8 b0 = *(const short8*)kb;
            short8 b1 = *(const short8*)(kb + 32);
            s0 = MFMA16(aq0, b0, s0);
            s0 = MFMA16(aq1, b1, s0);
            const u16* kb2 = kb + 16 * 64;
            short8 b2 = *(const short8*)kb2;
            short8 b3 = *(const short8*)(kb2 + 32);
            s1 = MFMA16(aq0, b2, s1);
            s1 = MFMA16(aq1, b3, s1);
        }
        const int j0c = k0 + col;
        const int j1c = j0c + 16;
        const bool vv0 = (j0c < NKEY_) && (j0c == 0 || mask8[b * N_ + j0c - 1]);
        const bool vv1 = (j1c < NKEY_) && mask8[b * N_ + j1c - 1];   // j1c >= 16
        float px0[4], px1[4];
#pragma unroll
        for (int r = 0; r < 4; ++r) {
            int iq = i0 + rg * 4 + r;
            float a  = (vv0 && j0c <= iq + 1) ? s0[r] : -1e30f;
            float c2 = (vv1 && j1c <= iq + 1) ? s1[r] : -1e30f;
            float rm = fmaxf(a, c2);
            rm = fmaxf(rm, __shfl_xor(rm, 1, 16));
            rm = fmaxf(rm, __shfl_xor(rm, 2, 16));
            rm = fmaxf(rm, __shfl_xor(rm, 4, 16));
            rm = fmaxf(rm, __shfl_xor(rm, 8, 16));
            float mnew = fmaxf(mr[r], rm);
            float cc = __expf(mr[r] - mnew);
            float p0 = __expf(a  - mnew);
            float p1 = __expf(c2 - mnew);
            float ps = p0 + p1;
            ps += __shfl_xor(ps, 1, 16);
            ps += __shfl_xor(ps, 2, 16);
            ps += __shfl_xor(ps, 4, 16);
            ps += __shfl_xor(ps, 8, 16);
            lr[r] = lr[r] * cc + ps;
            mr[r] = mnew;
            o0[r] *= cc; o1[r] *= cc; o2[r] *= cc; o3[r] *= cc;
            px0[r] = p0; px1[r] = p1;
        }
#pragma unroll
        for (int r = 0; r < 4; ++r) {
            plds[w][rg * 4 + r][col]      = f2bf(px0[r]);
            plds[w][rg * 4 + r][16 + col] = f2bf(px1[r]);
        }
        short8 pa = *(const short8*)&plds[w][col][rg * 8];
        {
            const u16* vb = Vt + ((size_t)b * 64 + col) * NKP_ + k0 + rg * 8;
            short8 bv0 = *(const short8*)vb;
            short8 bv1 = *(const short8*)(vb + 16 * NKP_);
            short8 bv2 = *(const short8*)(vb + 32 * NKP_);
            short8 bv3 = *(const short8*)(vb + 48 * NKP_);
            o0 = MFMA16(pa, bv0, o0);
            o1 = MFMA16(pa, bv1, o1);
            o2 = MFMA16(pa, bv2, o2);
            o3 = MFMA16(pa, bv3, o3);
        }
    }
    u16* ob = Out + (size_t)(b * N_ + i0 + rg * 4) * INNER_ + h * DH_ + col;
#pragma unroll
    for (int r = 0; r < 4; ++r) {
        float inv = 1.0f / lr[r];
        ob[(size_t)r * INNER_ + 0]  = f2bf(o0[r] * inv);
        ob[(size_t)r * INNER_ + 16] = f2bf(o1[r] * inv);
        ob[(size_t)r * INNER_ + 32] = f2bf(o2[r] * inv);
        ob[(size_t)r * INNER_ + 48] = f2bf(o3[r] * inv);
    }
}

// ---------------- launch ----------------
extern "C" void kernel_launch(void* const* d_in, const int* in_sizes, int n_in,
                              void* d_out, int out_size, void* d_ws, size_t ws_size,
                              hipStream_t stream) {
    const float* x       = (const float*)d_in[0];
    const void*  maskraw = d_in[1];
    const float* g_in    = (const float*)d_in[2];
    const float* Wq      = (const float*)d_in[3];
    const float* Wkv     = (const float*)d_in[4];
    const float* nullkv  = (const float*)d_in[5];
    const float* Wo      = (const float*)d_in[6];
    const float* g_out   = (const float*)d_in[7];
    float* out = (float*)d_out;

    char* ws = (char*)d_ws;
    size_t off = 0;
    auto alloc = [&](size_t bytes) {
        void* p = ws + off;
        off += (bytes + 255) & ~(size_t)255;
        return p;
    };
    int* flag   = (int*)alloc(4);
    u8* mask8   = (u8*)alloc((size_t)B_ * N_);
    u16* wq16   = (u16*)alloc((size_t)INNER_ * DIM_ * 2);
    u16* wkv16  = (u16*)alloc((size_t)128 * DIM_ * 2);
    u16* wo16   = (u16*)alloc((size_t)DIM_ * INNER_ * 2);
    u16* bufA   = (u16*)alloc((size_t)ROWS_ * DIM_ * 2);   // xn, later attn out
    u16* xb     = (u16*)alloc((size_t)ROWS_ * DIM_ * 2);   // bf16 copy of x
    u16* bufC   = (u16*)alloc((size_t)ROWS_ * INNER_ * 2); // q, later o-proj out
    float* kv   = (float*)alloc((size_t)ROWS_ * 128 * 4);
    u16* Kb     = (u16*)alloc((size_t)B_ * NKP_ * DH_ * 2);
    u16* Vt     = (u16*)alloc((size_t)B_ * DH_ * NKP_ * 2);

    detect_mask<<<1, 64, 0, stream>>>((const unsigned int*)maskraw, flag);
    canon_mask<<<(B_ * N_ + 255) / 256, 256, 0, stream>>>(maskraw, flag, mask8, B_ * N_);

    f32_to_bf16<<<(INNER_ * DIM_ / 4 + 255) / 256, 256, 0, stream>>>(Wq, wq16, INNER_ * DIM_ / 4);
    f32_to_bf16<<<(128 * DIM_ / 4 + 255) / 256, 256, 0, stream>>>(Wkv, wkv16, 128 * DIM_ / 4);
    f32_to_bf16<<<(DIM_ * INNER_ / 4 + 255) / 256, 256, 0, stream>>>(Wo, wo16, DIM_ * INNER_ / 4);

    ln_rows<0><<<ROWS_, 256, 0, stream>>>(x, g_in, bufA, xb);

    // Q = (LN(x) @ Wq^T) * 0.125 -> bf16
    gemm_mfma<true><<<dim3(INNER_ / 128, ROWS_ / 128), 256, 0, stream>>>(
        bufA, wq16, bufC, ROWS_, INNER_, DIM_, QK_SCALE_);

    // KV = x @ Wkv^T -> f32
    gemm_mfma<false><<<dim3(1, ROWS_ / 128), 256, 0, stream>>>(
        xb, wkv16, kv, ROWS_, 128, DIM_, 1.0f);

    build_kv<<<dim3(17, B_), 256, 0, stream>>>(kv, nullkv, Kb, Vt);

    attn_mfma<<<dim3(N_ / 64, B_ * HEADS_), 256, 0, stream>>>(bufC, Kb, Vt, mask8, bufA);

    // proj = attn @ Wo^T -> bf16
    gemm_mfma<true><<<dim3(DIM_ / 128, ROWS_ / 128), 256, 0, stream>>>(
        bufA, wo16, bufC, ROWS_, DIM_, INNER_, 1.0f);

    ln_rows<1><<<ROWS_, 256, 0, stream>>>(bufC, g_out, out, nullptr);
}

// Round 3
// 205.307 us; speedup vs baseline: 9.8217x; 1.6232x over previous
//
#include <hip/hip_runtime.h>
#include <hip/hip_bf16.h>

#define B_     8
#define N_     1024
#define DIM_   1024
#define HEADS_ 16
#define DH_    64
#define INNER_ 1024
#define NKEY_  1025
#define NKP_   1056      // keys padded to multiple of 32
#define NW_    33        // mask bitmask words per batch (NKP_/32)
#define ROWS_  8192
#define EPS_   1e-5f
#define QK_SCALE_ 0.125f   // DIM_HEAD^-0.5; ALPHA/pb-relax cancels in softmax

typedef unsigned short u16;
typedef unsigned char  u8;
typedef unsigned int   u32;
typedef __attribute__((ext_vector_type(8)))  short bf16x8;   // 8 bf16 = 4 VGPR
typedef __attribute__((ext_vector_type(4)))  float f32x4;
typedef __attribute__((ext_vector_type(16))) float f32x16;

__device__ __forceinline__ float bf2f(u16 u) {
    unsigned int x = ((unsigned int)u) << 16;
    return __uint_as_float(x);
}
__device__ __forceinline__ u16 f2bf(float f) {
    unsigned int x = __float_as_uint(f);
    x += 0x7FFFu + ((x >> 16) & 1u);   // RNE
    return (u16)(x >> 16);
}

#define MFMA16(a, b, c) __builtin_amdgcn_mfma_f32_16x16x32_bf16((a), (b), (c), 0, 0, 0)
#define MFMA32(a, b, c) __builtin_amdgcn_mfma_f32_32x32x16_bf16((a), (b), (c), 0, 0, 0)

__device__ __forceinline__ void gload16(const void* g, void* l) {
    __builtin_amdgcn_global_load_lds(
        (const __attribute__((address_space(1))) unsigned int*)g,
        (__attribute__((address_space(3))) unsigned int*)l, 16, 0, 0);
}

__device__ __forceinline__ u32 cvtpk(float lo, float hi) {
    u32 r;
    asm("v_cvt_pk_bf16_f32 %0, %1, %2" : "=v"(r) : "v"(lo), "v"(hi));
    return r;
}
__device__ __forceinline__ void plswap(u32& a, u32& b) {
    asm volatile("v_permlane32_swap_b32 %0, %1" : "+v"(a), "+v"(b));
}

// ---------------- mask representation handling ----------------
__global__ void detect_mask(const unsigned int* __restrict__ m, int* __restrict__ flag) {
    if (threadIdx.x == 0 && blockIdx.x == 0) {
        int f = 0;  // 0=int32, 1=bytes(bool), 2=float32
        for (int i = 0; i < 64; ++i) {
            unsigned int w = m[i];
            if (w == 0x3F800000u) { f = 2; break; }
            if (w > 1u) f = 1;
        }
        *flag = f;
    }
}

__global__ void canon_mask(const void* __restrict__ m, const int* __restrict__ flag,
                           u8* __restrict__ out, int n) {
    int i = blockIdx.x * blockDim.x + threadIdx.x;
    if (i >= n) return;
    int f = *flag;
    u8 r;
    if (f == 0)      r = (u8)(((const int*)m)[i] != 0);
    else if (f == 1) r = (u8)(((const u8*)m)[i] != 0);
    else             r = (u8)(((const float*)m)[i] != 0.0f);
    out[i] = r;
}

// visibility bitmask per (b, 32-key word): bit jp -> padding-visible
__global__ void build_bits(const u8* __restrict__ mask8, u32* __restrict__ vbits) {
    int tid = blockIdx.x * blockDim.x + threadIdx.x;
    if (tid >= B_ * NW_) return;
    int b = tid / NW_, wq = tid - b * NW_;
    u32 bits = 0;
    for (int i = 0; i < 32; ++i) {
        int jp = wq * 32 + i;
        bool vis = (jp == 0) || (jp < NKEY_ && mask8[b * N_ + jp - 1] != 0);
        if (vis) bits |= (1u << i);
    }
    vbits[tid] = bits;
}

// ---------------- f32 -> bf16 convert ----------------
__global__ void f32_to_bf16(const float* __restrict__ in, u16* __restrict__ out, int n4) {
    int i = blockIdx.x * blockDim.x + threadIdx.x;
    if (i >= n4) return;
    float4 v = ((const float4*)in)[i];
    ushort4 u; u.x = f2bf(v.x); u.y = f2bf(v.y); u.z = f2bf(v.z); u.w = f2bf(v.w);
    ((ushort4*)out)[i] = u;
}

// ---------------- layernorm over rows of 1024 ----------------
// MODE 0: f32 in -> bf16 LN out + bf16 raw copy; MODE 1: bf16 in -> f32 LN out
template<int MODE>
__global__ __launch_bounds__(256)
void ln_rows(const void* __restrict__ xv, const float* __restrict__ g,
             void* __restrict__ outv, u16* __restrict__ raw16) {
    int row = blockIdx.x;
    int t = threadIdx.x;
    float v0, v1, v2, v3;
    if constexpr (MODE == 0) {
        float4 v = ((const float4*)((const float*)xv + (size_t)row * DIM_))[t];
        v0 = v.x; v1 = v.y; v2 = v.z; v3 = v.w;
    } else {
        ushort4 u = ((const ushort4*)((const u16*)xv + (size_t)row * DIM_))[t];
        v0 = bf2f(u.x); v1 = bf2f(u.y); v2 = bf2f(u.z); v3 = bf2f(u.w);
    }
    float s  = v0 + v1 + v2 + v3;
    float ss = v0*v0 + v1*v1 + v2*v2 + v3*v3;
#pragma unroll
    for (int off = 32; off > 0; off >>= 1) {
        s  += __shfl_down(s,  off, 64);
        ss += __shfl_down(ss, off, 64);
    }
    __shared__ float red[10];
    int wid = t >> 6, lane = t & 63;
    if (lane == 0) { red[wid] = s; red[4 + wid] = ss; }
    __syncthreads();
    if (t == 0) {
        float S  = red[0] + red[1] + red[2] + red[3];
        float SS = red[4] + red[5] + red[6] + red[7];
        float mean = S * (1.0f / DIM_);
        float var  = SS * (1.0f / DIM_) - mean * mean;
        red[8] = mean;
        red[9] = rsqrtf(var + EPS_);
    }
    __syncthreads();
    float mean = red[8], rs = red[9];
    float4 gv = ((const float4*)g)[t];
    float o0 = (v0 - mean) * rs * gv.x;
    float o1 = (v1 - mean) * rs * gv.y;
    float o2 = (v2 - mean) * rs * gv.z;
    float o3 = (v3 - mean) * rs * gv.w;
    if constexpr (MODE == 0) {
        ushort4 u; u.x = f2bf(o0); u.y = f2bf(o1); u.z = f2bf(o2); u.w = f2bf(o3);
        ((ushort4*)((u16*)outv + (size_t)row * DIM_))[t] = u;
        ushort4 rw; rw.x = f2bf(v0); rw.y = f2bf(v1); rw.z = f2bf(v2); rw.w = f2bf(v3);
        ((ushort4*)(raw16 + (size_t)row * DIM_))[t] = rw;
    } else {
        float4 u; u.x = o0; u.y = o1; u.z = o2; u.w = o3;
        ((float4*)((float*)outv + (size_t)row * DIM_))[t] = u;
    }
}

// ---------------- MFMA GEMM: C = A(bf16 MxK) @ Bt(bf16 NxK)^T ----------------
template<bool BF16OUT>
__global__ __launch_bounds__(256)
void gemm_mfma(const u16* __restrict__ A, const u16* __restrict__ Bt,
               void* __restrict__ Cv, int M, int Nn, int K, float scale) {
    __shared__ u16 As[128 * 32];
    __shared__ u16 Bs[128 * 32];
    const int t = threadIdx.x;
    const int w = t >> 6, l = t & 63;
    const int col = l & 15, rg = l >> 4;
    const int wm = (w >> 1) * 64, wn = (w & 1) * 64;
    const int m0 = blockIdx.y * 128, n0 = blockIdx.x * 128;
    const int slr = l >> 2;
    const int slc = (l & 3) * 8;
    f32x4 acc[4][4];
#pragma unroll
    for (int i = 0; i < 4; ++i)
#pragma unroll
        for (int j = 0; j < 4; ++j) acc[i][j] = f32x4{0.f, 0.f, 0.f, 0.f};

    const u16* Abase = A  + (size_t)m0 * K;
    const u16* Bbase = Bt + (size_t)n0 * K;
    for (int k0 = 0; k0 < K; k0 += 32) {
        __syncthreads();
#pragma unroll
        for (int p = 0; p < 2; ++p) {
            int rb = w * 2 + p;
            gload16(Abase + (size_t)(rb * 16 + slr) * K + k0 + slc, &As[rb * 512]);
            gload16(Bbase + (size_t)(rb * 16 + slr) * K + k0 + slc, &Bs[rb * 512]);
        }
        __syncthreads();
        bf16x8 af[4], bf4[4];
#pragma unroll
        for (int mi = 0; mi < 4; ++mi)
            af[mi] = *(const bf16x8*)&As[(wm + mi * 16 + col) * 32 + rg * 8];
#pragma unroll
        for (int ni = 0; ni < 4; ++ni)
            bf4[ni] = *(const bf16x8*)&Bs[(wn + ni * 16 + col) * 32 + rg * 8];
#pragma unroll
        for (int mi = 0; mi < 4; ++mi)
#pragma unroll
            for (int ni = 0; ni < 4; ++ni)
                acc[mi][ni] = MFMA16(af[mi], bf4[ni], acc[mi][ni]);
    }
#pragma unroll
    for (int mi = 0; mi < 4; ++mi)
#pragma unroll
        for (int ni = 0; ni < 4; ++ni)
#pragma unroll
            for (int r = 0; r < 4; ++r) {
                int row = m0 + wm + mi * 16 + rg * 4 + r;
                int c   = n0 + wn + ni * 16 + col;
                float vv = acc[mi][ni][r] * scale;
                if constexpr (BF16OUT) ((u16*)Cv)[(size_t)row * Nn + c] = f2bf(vv);
                else                   ((float*)Cv)[(size_t)row * Nn + c] = vv;
            }
}

// ---------------- build K (row-major) and V^T (d-major), bf16, padded ----------------
__global__ __launch_bounds__(256)
void build_kv(const float* __restrict__ kv, const float* __restrict__ nullkv,
              u16* __restrict__ Kb, u16* __restrict__ Vt) {
    int jt = blockIdx.x;     // 17 tiles of 64 j
    int b  = blockIdx.y;
    __shared__ u16 vs[64][66];
    int t = threadIdx.x;
#pragma unroll
    for (int p = 0; p < 16; ++p) {
        int idx = p * 256 + t;
        int jl = idx >> 6, d = idx & 63;
        int j = jt * 64 + jl;
        float kf = 0.f, vf = 0.f;
        if (j == 0) { kf = nullkv[d]; vf = nullkv[64 + d]; }
        else if (j <= N_) {
            const float* row = kv + (size_t)(b * N_ + j - 1) * 128;
            kf = row[d]; vf = row[64 + d];
        }
        if (j < NKP_) Kb[((size_t)b * NKP_ + j) * 64 + d] = f2bf(kf);
        vs[d][jl] = f2bf(vf);
    }
    __syncthreads();
#pragma unroll
    for (int p = 0; p < 16; ++p) {
        int idx = p * 256 + t;
        int d = idx >> 6, jl = idx & 63;
        int j = jt * 64 + jl;
        if (j < NKP_) Vt[((size_t)b * 64 + d) * NKP_ + j] = vs[d][jl];
    }
}

// ---------------- 32x32 swapped-QK flash attention ----------------
// Wave owns 32 queries of one (b,h). S^T = mfma32(K, Q^T): lane holds 16 key
// scores for query col=l&31. Softmax in-register; P->bf16 B-frags via
// cvt_pk_bf16 + permlane32_swap; PV uses V^T as A-operand. No LDS.
template<bool CAUSAL>
__device__ __forceinline__ void attn_tile(
    const u16* __restrict__ Kbase, const u16* __restrict__ Vbase,
    int k0, int i0, int lo, int hi, u32 vbl, int lim,
    const bf16x8* qf, f32x16& o0, f32x16& o1, float& m_run, float& l_run)
{
    // ---- QK^T: S^T[key, q] over d = 0..63 (4 k-slices of 16) ----
    const u16* kp = Kbase + (size_t)(k0 + lo) * 64 + hi * 8;
    f32x16 s;
#pragma unroll
    for (int i = 0; i < 16; ++i) s[i] = 0.f;
#pragma unroll
    for (int dt = 0; dt < 4; ++dt) {
        bf16x8 kf = *(const bf16x8*)(kp + dt * 16);
        s = MFMA32(kf, qf[dt], s);
    }
    // ---- online softmax (max over raw scores is exact: shift-invariance) ----
    float mt = s[0];
#pragma unroll
    for (int r = 1; r < 16; ++r) mt = fmaxf(mt, s[r]);
    mt = fmaxf(mt, __shfl_xor(mt, 32, 64));
    if (!__all(mt <= m_run + 8.0f)) {          // defer-max (T13)
        float mn = fmaxf(m_run, mt);
        float c = __expf(m_run - mn);
        l_run *= c;
#pragma unroll
        for (int i = 0; i < 16; ++i) { o0[i] *= c; o1[i] *= c; }
        m_run = mn;
    }
    float p[16];
#pragma unroll
    for (int r = 0; r < 16; ++r) {
        const int ckr = (r & 3) + 8 * (r >> 2);   // key row (minus 4*hi)
        float pv = __expf(s[r] - m_run);
        bool ok = (vbl >> ckr) & 1u;
        if (CAUSAL) ok = ok && (ckr <= lim);
        p[r] = ok ? pv : 0.f;
    }
    float ls = 0.f;
#pragma unroll
    for (int r = 0; r < 16; ++r) ls += p[r];
    ls += __shfl_xor(ls, 32, 64);
    l_run += ls;
    // ---- pack P^T into B-fragments (keys 0..15 and 16..31) ----
    u32 w0 = cvtpk(p[0],  p[1]),  w2 = cvtpk(p[4],  p[5]);  plswap(w0, w2);
    u32 w1 = cvtpk(p[2],  p[3]),  w3 = cvtpk(p[6],  p[7]);  plswap(w1, w3);
    u32 w4 = cvtpk(p[8],  p[9]),  w6 = cvtpk(p[12], p[13]); plswap(w4, w6);
    u32 w5 = cvtpk(p[10], p[11]), w7 = cvtpk(p[14], p[15]); plswap(w5, w7);
    union { u32 w[4]; bf16x8 v; } f0, f1;
    f0.w[0] = w0; f0.w[1] = w1; f0.w[2] = w2; f0.w[3] = w3;
    f1.w[0] = w4; f1.w[1] = w5; f1.w[2] = w6; f1.w[3] = w7;
    // ---- PV: O^T[d, q] += V^T-frag (A) x P^T-frag (B) ----
    const u16* vp = Vbase + (size_t)lo * NKP_ + k0 + hi * 8;
    bf16x8 va00 = *(const bf16x8*)(vp);
    bf16x8 va01 = *(const bf16x8*)(vp + 16);
    o0 = MFMA32(va00, f0.v, o0);
    o0 = MFMA32(va01, f1.v, o0);
    const u16* vp1 = vp + (size_t)32 * NKP_;
    bf16x8 va10 = *(const bf16x8*)(vp1);
    bf16x8 va11 = *(const bf16x8*)(vp1 + 16);
    o1 = MFMA32(va10, f0.v, o1);
    o1 = MFMA32(va11, f1.v, o1);
}

__global__ __launch_bounds__(256)
void attn32(const u16* __restrict__ Q, const u16* __restrict__ Kb,
            const u16* __restrict__ Vt, const u32* __restrict__ vbits,
            u16* __restrict__ Out) {
    const int t = threadIdx.x;
    const int w = t >> 6, l = t & 63;
    const int lo = l & 31, hi = l >> 5;
    const int bx = blockIdx.x;    // 0..7; pair heavy+light q-tiles per block
    int qt;
    if      (w == 0) qt = bx * 2;
    else if (w == 1) qt = bx * 2 + 1;
    else if (w == 2) qt = 31 - bx * 2;
    else             qt = 30 - bx * 2;
    const int i0 = qt * 32;
    const int b = blockIdx.y >> 4, h = blockIdx.y & 15;

    bf16x8 qf[4];
    const u16* qp = Q + (size_t)(b * N_ + i0 + lo) * INNER_ + h * DH_ + hi * 8;
#pragma unroll
    for (int dt = 0; dt < 4; ++dt) qf[dt] = *(const bf16x8*)(qp + dt * 16);

    f32x16 o0, o1;
#pragma unroll
    for (int i = 0; i < 16; ++i) { o0[i] = 0.f; o1[i] = 0.f; }
    float m_run = -3.0e38f, l_run = 0.f;

    const u16* Kbase = Kb + (size_t)b * NKP_ * 64;
    const u16* Vbase = Vt + (size_t)b * 64 * NKP_;
    const u32* vbb = vbits + b * NW_;

    for (int kt = 0; kt < qt; ++kt) {          // fully causal-visible tiles
        u32 vb = vbb[kt];
        u32 vbl = hi ? (vb >> 4) : vb;
        attn_tile<false>(Kbase, Vbase, kt * 32, i0, lo, hi, vbl, 0,
                         qf, o0, o1, m_run, l_run);
    }
#pragma unroll
    for (int e = 0; e < 2; ++e) {              // causal boundary tiles
        int kt = qt + e;
        u32 vb = vbb[kt];
        u32 vbl = hi ? (vb >> 4) : vb;
        int lim = i0 + lo + 1 - kt * 32 - 4 * hi;
        attn_tile<true>(Kbase, Vbase, kt * 32, i0, lo, hi, vbl, lim,
                        qf, o0, o1, m_run, l_run);
    }

    float inv = 1.0f / l_run;
    u16* ob = Out + (size_t)(b * N_ + i0 + lo) * INNER_ + h * DH_;
#pragma unroll
    for (int dd = 0; dd < 2; ++dd) {
#pragma unroll
        for (int g = 0; g < 4; ++g) {
            int d0 = dd * 32 + 8 * g + 4 * hi;
            float e0 = (dd ? o1[4*g+0] : o0[4*g+0]) * inv;
            float e1 = (dd ? o1[4*g+1] : o0[4*g+1]) * inv;
            float e2 = (dd ? o1[4*g+2] : o0[4*g+2]) * inv;
            float e3 = (dd ? o1[4*g+3] : o0[4*g+3]) * inv;
            ushort4 u; u.x = f2bf(e0); u.y = f2bf(e1); u.z = f2bf(e2); u.w = f2bf(e3);
            *(ushort4*)(ob + d0) = u;
        }
    }
}

// ---------------- launch ----------------
extern "C" void kernel_launch(void* const* d_in, const int* in_sizes, int n_in,
                              void* d_out, int out_size, void* d_ws, size_t ws_size,
                              hipStream_t stream) {
    const float* x       = (const float*)d_in[0];
    const void*  maskraw = d_in[1];
    const float* g_in    = (const float*)d_in[2];
    const float* Wq      = (const float*)d_in[3];
    const float* Wkv     = (const float*)d_in[4];
    const float* nullkv  = (const float*)d_in[5];
    const float* Wo      = (const float*)d_in[6];
    const float* g_out   = (const float*)d_in[7];
    float* out = (float*)d_out;

    char* ws = (char*)d_ws;
    size_t off = 0;
    auto alloc = [&](size_t bytes) {
        void* p = ws + off;
        off += (bytes + 255) & ~(size_t)255;
        return p;
    };
    int* flag   = (int*)alloc(4);
    u8* mask8   = (u8*)alloc((size_t)B_ * N_);
    u32* vbits  = (u32*)alloc((size_t)B_ * NW_ * 4);
    u16* wq16   = (u16*)alloc((size_t)INNER_ * DIM_ * 2);
    u16* wkv16  = (u16*)alloc((size_t)128 * DIM_ * 2);
    u16* wo16   = (u16*)alloc((size_t)DIM_ * INNER_ * 2);
    u16* bufA   = (u16*)alloc((size_t)ROWS_ * DIM_ * 2);   // xn, later attn out
    u16* xb     = (u16*)alloc((size_t)ROWS_ * DIM_ * 2);   // bf16 copy of x
    u16* bufC   = (u16*)alloc((size_t)ROWS_ * INNER_ * 2); // q, later o-proj out
    float* kv   = (float*)alloc((size_t)ROWS_ * 128 * 4);
    u16* Kb     = (u16*)alloc((size_t)B_ * NKP_ * DH_ * 2);
    u16* Vt     = (u16*)alloc((size_t)B_ * DH_ * NKP_ * 2);

    detect_mask<<<1, 64, 0, stream>>>((const unsigned int*)maskraw, flag);
    canon_mask<<<(B_ * N_ + 255) / 256, 256, 0, stream>>>(maskraw, flag, mask8, B_ * N_);
    build_bits<<<2, 256, 0, stream>>>(mask8, vbits);

    f32_to_bf16<<<(INNER_ * DIM_ / 4 + 255) / 256, 256, 0, stream>>>(Wq, wq16, INNER_ * DIM_ / 4);
    f32_to_bf16<<<(128 * DIM_ / 4 + 255) / 256, 256, 0, stream>>>(Wkv, wkv16, 128 * DIM_ / 4);
    f32_to_bf16<<<(DIM_ * INNER_ / 4 + 255) / 256, 256, 0, stream>>>(Wo, wo16, DIM_ * INNER_ / 4);

    ln_rows<0><<<ROWS_, 256, 0, stream>>>(x, g_in, bufA, xb);

    // Q = (LN(x) @ Wq^T) * 0.125 -> bf16
    gemm_mfma<true><<<dim3(INNER_ / 128, ROWS_ / 128), 256, 0, stream>>>(
        bufA, wq16, bufC, ROWS_, INNER_, DIM_, QK_SCALE_);

    // KV = x @ Wkv^T -> f32
    gemm_mfma<false><<<dim3(1, ROWS_ / 128), 256, 0, stream>>>(
        xb, wkv16, kv, ROWS_, 128, DIM_, 1.0f);

    build_kv<<<dim3(17, B_), 256, 0, stream>>>(kv, nullkv, Kb, Vt);

    attn32<<<dim3(8, B_ * HEADS_), 256, 0, stream>>>(bufC, Kb, Vt, vbits, bufA);

    // proj = attn @ Wo^T -> bf16
    gemm_mfma<true><<<dim3(DIM_ / 128, ROWS_ / 128), 256, 0, stream>>>(
        bufA, wo16, bufC, ROWS_, DIM_, INNER_, 1.0f);

    ln_rows<1><<<ROWS_, 256, 0, stream>>>(bufC, g_out, out, nullptr);
}

// Round 4
// 196.134 us; speedup vs baseline: 10.2810x; 1.0468x over previous
//
#include <hip/hip_runtime.h>
#include <hip/hip_bf16.h>

#define B_     8
#define N_     1024
#define DIM_   1024
#define HEADS_ 16
#define DH_    64
#define INNER_ 1024
#define NKEY_  1025
#define NTILE_ 33        // kv tiles of 32 keys
#define NW_    33        // vbits words per batch
#define ROWS_  8192
#define EPS_   1e-5f
#define QK_SCALE_ 0.125f   // DIM_HEAD^-0.5; ALPHA/pb-relax cancels in softmax
#define KVT_BYTES_ 9216    // per-tile staged bytes: 4096 K + 5120 V(padded)
#define KVT_ELEMS_ 4608

typedef unsigned short u16;
typedef unsigned char  u8;
typedef unsigned int   u32;
typedef __attribute__((ext_vector_type(8)))  short bf16x8;
typedef __attribute__((ext_vector_type(4)))  float f32x4;
typedef __attribute__((ext_vector_type(16))) float f32x16;

__device__ __forceinline__ float bf2f(u16 u) {
    unsigned int x = ((unsigned int)u) << 16;
    return __uint_as_float(x);
}
__device__ __forceinline__ u16 f2bf(float f) {
    unsigned int x = __float_as_uint(f);
    x += 0x7FFFu + ((x >> 16) & 1u);   // RNE
    return (u16)(x >> 16);
}

#define MFMA16(a, b, c) __builtin_amdgcn_mfma_f32_16x16x32_bf16((a), (b), (c), 0, 0, 0)
#define MFMA32(a, b, c) __builtin_amdgcn_mfma_f32_32x32x16_bf16((a), (b), (c), 0, 0, 0)

__device__ __forceinline__ void gload16(const void* g, void* l) {
    __builtin_amdgcn_global_load_lds(
        (const __attribute__((address_space(1))) unsigned int*)g,
        (__attribute__((address_space(3))) unsigned int*)l, 16, 0, 0);
}

__device__ __forceinline__ u32 cvtpk(float lo, float hi) {
    u32 r;
    asm("v_cvt_pk_bf16_f32 %0, %1, %2" : "=v"(r) : "v"(lo), "v"(hi));
    return r;
}
__device__ __forceinline__ void plswap(u32& a, u32& b) {
    asm volatile("v_permlane32_swap_b32 %0, %1" : "+v"(a), "+v"(b));
}

// ---------------- mask representation handling ----------------
__global__ void detect_mask(const unsigned int* __restrict__ m, int* __restrict__ flag) {
    if (threadIdx.x == 0 && blockIdx.x == 0) {
        int f = 0;  // 0=int32, 1=bytes(bool), 2=float32
        for (int i = 0; i < 64; ++i) {
            unsigned int w = m[i];
            if (w == 0x3F800000u) { f = 2; break; }
            if (w > 1u) f = 1;
        }
        *flag = f;
    }
}

// visibility bitmask per (b, 32-key word), read directly from raw mask
__global__ void build_bits(const void* __restrict__ mraw, const int* __restrict__ flag,
                           u32* __restrict__ vbits) {
    int tid = blockIdx.x * blockDim.x + threadIdx.x;
    if (tid >= B_ * NW_) return;
    int b = tid / NW_, wq = tid - b * NW_;
    int f = *flag;
    u32 bits = 0;
    for (int i = 0; i < 32; ++i) {
        int jp = wq * 32 + i;
        bool vis;
        if (jp == 0) vis = true;
        else if (jp < NKEY_) {
            int idx = b * N_ + jp - 1;
            if (f == 0)      vis = ((const int*)mraw)[idx] != 0;
            else if (f == 1) vis = ((const u8*)mraw)[idx] != 0;
            else             vis = ((const float*)mraw)[idx] != 0.0f;
        } else vis = false;
        if (vis) bits |= (1u << i);
    }
    vbits[tid] = bits;
}

// ---------------- merged f32 -> bf16 weight convert ----------------
__global__ void cvt_w(const float* __restrict__ wq, const float* __restrict__ wkv,
                      const float* __restrict__ wo, u16* __restrict__ q16,
                      u16* __restrict__ kv16, u16* __restrict__ o16) {
    int i = blockIdx.x * blockDim.x + threadIdx.x;   // unit = 4 elems
    const int NQ = INNER_ * DIM_ / 4, NKV = 128 * DIM_ / 4, NO = DIM_ * INNER_ / 4;
    const float* src; u16* dst; int off;
    if (i < NQ)            { src = wq;  dst = q16;  off = i; }
    else if (i < NQ + NKV) { src = wkv; dst = kv16; off = i - NQ; }
    else if (i < NQ + NKV + NO) { src = wo; dst = o16; off = i - NQ - NKV; }
    else return;
    float4 v = ((const float4*)src)[off];
    ushort4 u; u.x = f2bf(v.x); u.y = f2bf(v.y); u.z = f2bf(v.z); u.w = f2bf(v.w);
    ((ushort4*)dst)[off] = u;
}

// ---------------- layernorm over rows of 1024 ----------------
template<int MODE>   // 0: f32 in -> bf16 LN out + bf16 raw copy; 1: bf16 in -> f32 out
__global__ __launch_bounds__(256)
void ln_rows(const void* __restrict__ xv, const float* __restrict__ g,
             void* __restrict__ outv, u16* __restrict__ raw16) {
    int row = blockIdx.x;
    int t = threadIdx.x;
    float v0, v1, v2, v3;
    if constexpr (MODE == 0) {
        float4 v = ((const float4*)((const float*)xv + (size_t)row * DIM_))[t];
        v0 = v.x; v1 = v.y; v2 = v.z; v3 = v.w;
    } else {
        ushort4 u = ((const ushort4*)((const u16*)xv + (size_t)row * DIM_))[t];
        v0 = bf2f(u.x); v1 = bf2f(u.y); v2 = bf2f(u.z); v3 = bf2f(u.w);
    }
    float s  = v0 + v1 + v2 + v3;
    float ss = v0*v0 + v1*v1 + v2*v2 + v3*v3;
#pragma unroll
    for (int off = 32; off > 0; off >>= 1) {
        s  += __shfl_down(s,  off, 64);
        ss += __shfl_down(ss, off, 64);
    }
    __shared__ float red[10];
    int wid = t >> 6, lane = t & 63;
    if (lane == 0) { red[wid] = s; red[4 + wid] = ss; }
    __syncthreads();
    if (t == 0) {
        float S  = red[0] + red[1] + red[2] + red[3];
        float SS = red[4] + red[5] + red[6] + red[7];
        float mean = S * (1.0f / DIM_);
        float var  = SS * (1.0f / DIM_) - mean * mean;
        red[8] = mean;
        red[9] = rsqrtf(var + EPS_);
    }
    __syncthreads();
    float mean = red[8], rs = red[9];
    float4 gv = ((const float4*)g)[t];
    float o0 = (v0 - mean) * rs * gv.x;
    float o1 = (v1 - mean) * rs * gv.y;
    float o2 = (v2 - mean) * rs * gv.z;
    float o3 = (v3 - mean) * rs * gv.w;
    if constexpr (MODE == 0) {
        ushort4 u; u.x = f2bf(o0); u.y = f2bf(o1); u.z = f2bf(o2); u.w = f2bf(o3);
        ((ushort4*)((u16*)outv + (size_t)row * DIM_))[t] = u;
        ushort4 rw; rw.x = f2bf(v0); rw.y = f2bf(v1); rw.z = f2bf(v2); rw.w = f2bf(v3);
        ((ushort4*)(raw16 + (size_t)row * DIM_))[t] = rw;
    } else {
        float4 u; u.x = o0; u.y = o1; u.z = o2; u.w = o3;
        ((float4*)((float*)outv + (size_t)row * DIM_))[t] = u;
    }
}

// ---------------- fused Q-proj + KV-proj (m97 structure, K=1024) ----------------
__global__ __launch_bounds__(256)
void proj_fused(const u16* __restrict__ xn, const u16* __restrict__ xraw,
                const u16* __restrict__ wq, const u16* __restrict__ wkv,
                u16* __restrict__ qout, float* __restrict__ kvout) {
    __shared__ u16 As[128 * 32];
    __shared__ u16 Bs[128 * 32];
    const bool iskv = (blockIdx.x == 8);
    const u16* A  = iskv ? xraw : xn;
    const u16* Bt = iskv ? wkv : wq;
    const int  Nn = iskv ? 128 : INNER_;
    const int  n0 = iskv ? 0 : blockIdx.x * 128;
    const float scale = iskv ? 1.0f : QK_SCALE_;
    const int t = threadIdx.x;
    const int w = t >> 6, l = t & 63;
    const int col = l & 15, rg = l >> 4;
    const int wm = (w >> 1) * 64, wn = (w & 1) * 64;
    const int m0 = blockIdx.y * 128;
    const int slr = l >> 2;
    const int slc = (l & 3) * 8;
    f32x4 acc[4][4];
#pragma unroll
    for (int i = 0; i < 4; ++i)
#pragma unroll
        for (int j = 0; j < 4; ++j) acc[i][j] = f32x4{0.f, 0.f, 0.f, 0.f};

    const u16* Abase = A  + (size_t)m0 * DIM_;
    const u16* Bbase = Bt + (size_t)n0 * DIM_;
    for (int k0 = 0; k0 < DIM_; k0 += 32) {
        __syncthreads();
#pragma unroll
        for (int p = 0; p < 2; ++p) {
            int rb = w * 2 + p;
            gload16(Abase + (size_t)(rb * 16 + slr) * DIM_ + k0 + slc, &As[rb * 512]);
            gload16(Bbase + (size_t)(rb * 16 + slr) * DIM_ + k0 + slc, &Bs[rb * 512]);
        }
        __syncthreads();
        bf16x8 af[4], bf4[4];
#pragma unroll
        for (int mi = 0; mi < 4; ++mi)
            af[mi] = *(const bf16x8*)&As[(wm + mi * 16 + col) * 32 + rg * 8];
#pragma unroll
        for (int ni = 0; ni < 4; ++ni)
            bf4[ni] = *(const bf16x8*)&Bs[(wn + ni * 16 + col) * 32 + rg * 8];
#pragma unroll
        for (int mi = 0; mi < 4; ++mi)
#pragma unroll
            for (int ni = 0; ni < 4; ++ni)
                acc[mi][ni] = MFMA16(af[mi], bf4[ni], acc[mi][ni]);
    }
#pragma unroll
    for (int mi = 0; mi < 4; ++mi)
#pragma unroll
        for (int ni = 0; ni < 4; ++ni)
#pragma unroll
            for (int r = 0; r < 4; ++r) {
                size_t row = (size_t)(m0 + wm + mi * 16 + rg * 4 + r);
                int c = n0 + wn + ni * 16 + col;
                float vv = acc[mi][ni][r] * scale;
                if (iskv) kvout[row * 128 + c] = vv;
                else      qout[row * INNER_ + c] = f2bf(vv);
            }
}

// ---------------- MFMA GEMM for O-projection ----------------
__global__ __launch_bounds__(256)
void gemm_o(const u16* __restrict__ A, const u16* __restrict__ Bt,
            u16* __restrict__ Cv) {
    __shared__ u16 As[128 * 32];
    __shared__ u16 Bs[128 * 32];
    const int t = threadIdx.x;
    const int w = t >> 6, l = t & 63;
    const int col = l & 15, rg = l >> 4;
    const int wm = (w >> 1) * 64, wn = (w & 1) * 64;
    const int m0 = blockIdx.y * 128, n0 = blockIdx.x * 128;
    const int slr = l >> 2;
    const int slc = (l & 3) * 8;
    f32x4 acc[4][4];
#pragma unroll
    for (int i = 0; i < 4; ++i)
#pragma unroll
        for (int j = 0; j < 4; ++j) acc[i][j] = f32x4{0.f, 0.f, 0.f, 0.f};
    const u16* Abase = A  + (size_t)m0 * INNER_;
    const u16* Bbase = Bt + (size_t)n0 * INNER_;
    for (int k0 = 0; k0 < INNER_; k0 += 32) {
        __syncthreads();
#pragma unroll
        for (int p = 0; p < 2; ++p) {
            int rb = w * 2 + p;
            gload16(Abase + (size_t)(rb * 16 + slr) * INNER_ + k0 + slc, &As[rb * 512]);
            gload16(Bbase + (size_t)(rb * 16 + slr) * INNER_ + k0 + slc, &Bs[rb * 512]);
        }
        __syncthreads();
        bf16x8 af[4], bf4[4];
#pragma unroll
        for (int mi = 0; mi < 4; ++mi)
            af[mi] = *(const bf16x8*)&As[(wm + mi * 16 + col) * 32 + rg * 8];
#pragma unroll
        for (int ni = 0; ni < 4; ++ni)
            bf4[ni] = *(const bf16x8*)&Bs[(wn + ni * 16 + col) * 32 + rg * 8];
#pragma unroll
        for (int mi = 0; mi < 4; ++mi)
#pragma unroll
            for (int ni = 0; ni < 4; ++ni)
                acc[mi][ni] = MFMA16(af[mi], bf4[ni], acc[mi][ni]);
    }
#pragma unroll
    for (int mi = 0; mi < 4; ++mi)
#pragma unroll
        for (int ni = 0; ni < 4; ++ni)
#pragma unroll
            for (int r = 0; r < 4; ++r) {
                size_t row = (size_t)(m0 + wm + mi * 16 + rg * 4 + r);
                int c = n0 + wn + ni * 16 + col;
                Cv[row * DIM_ + c] = f2bf(acc[mi][ni][r]);
            }
}

// ---------------- build combined staged K/V tiles ----------------
// Per (b, kt): [32][64] K swizzled (d ^= (j&7)<<3) then [64][40] V^T padded.
__global__ __launch_bounds__(256)
void build_kv(const float* __restrict__ kvf, const float* __restrict__ nullkv,
              u16* __restrict__ KVsw) {
    const int kt = blockIdx.x, b = blockIdx.y;
    const int t = threadIdx.x;
    const int k0 = kt * 32;
    u16* base = KVsw + ((size_t)b * NTILE_ + kt) * KVT_ELEMS_;
    // K part: 2048 elems, 8 per thread (dest-contiguous)
    {
        int j = t >> 3;
        int dsw0 = (t & 7) * 8;
        int dsrc0 = dsw0 ^ ((j & 7) << 3);
        int jp = k0 + j;
        float v[8];
        if (jp == 0) {
#pragma unroll
            for (int i = 0; i < 8; ++i) v[i] = nullkv[dsrc0 + i];
        } else if (jp <= N_) {
            const float* r = kvf + ((size_t)b * N_ + jp - 1) * 128 + dsrc0;
            float4 a = ((const float4*)r)[0], c = ((const float4*)r)[1];
            v[0]=a.x; v[1]=a.y; v[2]=a.z; v[3]=a.w; v[4]=c.x; v[5]=c.y; v[6]=c.z; v[7]=c.w;
        } else {
#pragma unroll
            for (int i = 0; i < 8; ++i) v[i] = 0.f;
        }
        ushort4 u0, u1;
        u0.x=f2bf(v[0]); u0.y=f2bf(v[1]); u0.z=f2bf(v[2]); u0.w=f2bf(v[3]);
        u1.x=f2bf(v[4]); u1.y=f2bf(v[5]); u1.z=f2bf(v[6]); u1.w=f2bf(v[7]);
        *(ushort4*)(base + j * 64 + dsw0)     = u0;
        *(ushort4*)(base + j * 64 + dsw0 + 4) = u1;
    }
    // V part: rows d 0..63 x 40 cols (cols 32..39 pad) = 320 units of 8
    for (int u = t; u < 320; u += 256) {
        int d = u / 5;
        int jj0 = (u % 5) * 8;
        u16 o8[8];
#pragma unroll
        for (int i = 0; i < 8; ++i) {
            int jj = jj0 + i;
            float val = 0.f;
            if (jj < 32) {
                int jp = k0 + jj;
                if (jp == 0) val = nullkv[64 + d];
                else if (jp <= N_) val = kvf[((size_t)b * N_ + jp - 1) * 128 + 64 + d];
            }
            o8[i] = f2bf(val);
        }
        u16* dst = base + 2048 + d * 40 + jj0;
        ushort4 u0, u1;
        u0.x=o8[0]; u0.y=o8[1]; u0.z=o8[2]; u0.w=o8[3];
        u1.x=o8[4]; u1.y=o8[5]; u1.z=o8[6]; u1.w=o8[7];
        *(ushort4*)dst = u0;
        *(ushort4*)(dst + 4) = u1;
    }
}

// ---------------- paired, head-shared, LDS-staged flash attention ----------------
__device__ __forceinline__ void softmax_pv(
    f32x16& s, float& m, float& lsum, f32x16& o0, f32x16& o1,
    bool caus, int lim,
    const bf16x8& v00, const bf16x8& v01, const bf16x8& v10, const bf16x8& v11)
{
    float m01 = fmaxf(fmaxf(s[0], s[1]), fmaxf(s[2], s[3]));
    float m23 = fmaxf(fmaxf(s[4], s[5]), fmaxf(s[6], s[7]));
    float m45 = fmaxf(fmaxf(s[8], s[9]), fmaxf(s[10], s[11]));
    float m67 = fmaxf(fmaxf(s[12], s[13]), fmaxf(s[14], s[15]));
    float mt = fmaxf(fmaxf(m01, m23), fmaxf(m45, m67));
    mt = fmaxf(mt, __shfl_xor(mt, 32, 64));
    if (!__all(mt <= m + 8.0f)) {              // defer-max (T13)
        float mn = fmaxf(m, mt);
        float c = __expf(m - mn);
        lsum *= c;
#pragma unroll
        for (int i = 0; i < 16; ++i) { o0[i] *= c; o1[i] *= c; }
        m = mn;
    }
    float p[16];
#pragma unroll
    for (int r = 0; r < 16; ++r) p[r] = __expf(s[r] - m);
    if (caus) {
#pragma unroll
        for (int r = 0; r < 16; ++r)
            if (((r & 3) + 8 * (r >> 2)) > lim) p[r] = 0.f;
    }
    float ls = (((p[0]+p[1])+(p[2]+p[3])) + ((p[4]+p[5])+(p[6]+p[7])))
             + (((p[8]+p[9])+(p[10]+p[11])) + ((p[12]+p[13])+(p[14]+p[15])));
    ls += __shfl_xor(ls, 32, 64);
    lsum += ls;
    u32 w0 = cvtpk(p[0],  p[1]),  w2 = cvtpk(p[4],  p[5]);  plswap(w0, w2);
    u32 w1 = cvtpk(p[2],  p[3]),  w3 = cvtpk(p[6],  p[7]);  plswap(w1, w3);
    u32 w4 = cvtpk(p[8],  p[9]),  w6 = cvtpk(p[12], p[13]); plswap(w4, w6);
    u32 w5 = cvtpk(p[10], p[11]), w7 = cvtpk(p[14], p[15]); plswap(w5, w7);
    union { u32 wd[4]; bf16x8 v; } f0, f1;
    f0.wd[0] = w0; f0.wd[1] = w1; f0.wd[2] = w2; f0.wd[3] = w3;
    f1.wd[0] = w4; f1.wd[1] = w5; f1.wd[2] = w6; f1.wd[3] = w7;
    __builtin_amdgcn_s_setprio(1);
    o0 = MFMA32(v00, f0.v, o0);
    o0 = MFMA32(v01, f1.v, o0);
    o1 = MFMA32(v10, f0.v, o1);
    o1 = MFMA32(v11, f1.v, o1);
    __builtin_amdgcn_s_setprio(0);
}

__device__ __forceinline__ void write_o(u16* __restrict__ Out, int b, int i0, int lo,
                                        int hi, int h, float lsum,
                                        const f32x16& o0, const f32x16& o1) {
    float inv = 1.0f / lsum;
    u16* ob = Out + ((size_t)(b * N_ + i0 + lo)) * INNER_ + h * DH_;
#pragma unroll
    for (int dd = 0; dd < 2; ++dd)
#pragma unroll
        for (int g = 0; g < 4; ++g) {
            int d0 = dd * 32 + 8 * g + 4 * hi;
            float e0 = (dd ? o1[4*g+0] : o0[4*g+0]) * inv;
            float e1 = (dd ? o1[4*g+1] : o0[4*g+1]) * inv;
            float e2 = (dd ? o1[4*g+2] : o0[4*g+2]) * inv;
            float e3 = (dd ? o1[4*g+3] : o0[4*g+3]) * inv;
            ushort4 u; u.x = f2bf(e0); u.y = f2bf(e1); u.z = f2bf(e2); u.w = f2bf(e3);
            *(ushort4*)(ob + d0) = u;
        }
}

__global__ __launch_bounds__(256)
void attn32(const u16* __restrict__ Q, const u16* __restrict__ KVsw,
            const u32* __restrict__ vbits, u16* __restrict__ Out) {
    __shared__ __align__(16) u16 KV[2][KVT_ELEMS_];
    const int t = threadIdx.x;
    const int w = t >> 6, l = t & 63;
    const int lo = l & 31, hi = l >> 5;
    const int y = blockIdx.y;
    const int b = y >> 2, hg = y & 3;
    const int h = hg * 4 + w;
    // complementary pairing so co-resident blocks have equal total work
    const int qpa = (b < 4) ? blockIdx.x : 15 - blockIdx.x;
    const int qta = qpa, qtb = 31 - qpa;
    const int i0a = qta * 32, i0b = qtb * 32;
    const int nt = qtb + 2;

    bf16x8 qfa[4], qfb[4];
    {
        const u16* qpA = Q + ((size_t)(b * N_ + i0a + lo)) * INNER_ + h * DH_ + hi * 8;
        const u16* qpB = Q + ((size_t)(b * N_ + i0b + lo)) * INNER_ + h * DH_ + hi * 8;
#pragma unroll
        for (int dt = 0; dt < 4; ++dt) {
            qfa[dt] = *(const bf16x8*)(qpA + dt * 16);
            qfb[dt] = *(const bf16x8*)(qpB + dt * 16);
        }
    }
    f32x16 oa0, oa1, ob0, ob1;
#pragma unroll
    for (int i = 0; i < 16; ++i) { oa0[i]=0.f; oa1[i]=0.f; ob0[i]=0.f; ob1[i]=0.f; }
    float ma = -3.0e38f, la = 0.f, mb = -3.0e38f, lb = 0.f;

    const char* gbase = (const char*)(KVsw + (size_t)b * NTILE_ * KVT_ELEMS_);
    const u32* vbp = vbits + b * NW_;

    for (int seg = w; seg < 9; seg += 4)
        gload16(gbase + seg * 1024 + (size_t)l * 16, (char*)&KV[0][0] + seg * 1024);
    __syncthreads();

    int buf = 0;
    for (int kt = 0; kt < nt; ++kt) {
        if (kt + 1 < nt) {
            const char* gt = gbase + (size_t)(kt + 1) * KVT_BYTES_;
            for (int seg = w; seg < 9; seg += 4)
                gload16(gt + seg * 1024 + (size_t)l * 16,
                        (char*)&KV[buf ^ 1][0] + seg * 1024);
        }
        const char* Kl = (const char*)&KV[buf][0];
        const char* Vl = (const char*)&KV[buf][2048];
        bf16x8 kf0 = *(const bf16x8*)(Kl + lo*128 + ((hi*16 +  0) ^ ((lo & 7) << 4)));
        bf16x8 kf1 = *(const bf16x8*)(Kl + lo*128 + ((hi*16 + 32) ^ ((lo & 7) << 4)));
        bf16x8 kf2 = *(const bf16x8*)(Kl + lo*128 + ((hi*16 + 64) ^ ((lo & 7) << 4)));
        bf16x8 kf3 = *(const bf16x8*)(Kl + lo*128 + ((hi*16 + 96) ^ ((lo & 7) << 4)));
        u32 vb = vbp[kt];
        union { u32 wd[4]; bf16x8 v; } bias, ones;
        bias.wd[0] = (hi == 0 && !((vb >> lo) & 1u)) ? 0xC6E0u : 0u;  // bf16 -28672
        bias.wd[1] = 0; bias.wd[2] = 0; bias.wd[3] = 0;
        ones.wd[0] = (hi == 0) ? 0x3F80u : 0u;                        // bf16 1.0
        ones.wd[1] = 0; ones.wd[2] = 0; ones.wd[3] = 0;

        const bool aliv = (kt <= qta + 1);
        const int k0 = kt * 32;
        f32x16 sa, sb;
        __builtin_amdgcn_s_setprio(1);
        if (aliv) {
#pragma unroll
            for (int i = 0; i < 16; ++i) sa[i] = 0.f;
            sa = MFMA32(kf0, qfa[0], sa);
            sa = MFMA32(kf1, qfa[1], sa);
            sa = MFMA32(kf2, qfa[2], sa);
            sa = MFMA32(kf3, qfa[3], sa);
            sa = MFMA32(bias.v, ones.v, sa);
        }
#pragma unroll
        for (int i = 0; i < 16; ++i) sb[i] = 0.f;
        sb = MFMA32(kf0, qfb[0], sb);
        sb = MFMA32(kf1, qfb[1], sb);
        sb = MFMA32(kf2, qfb[2], sb);
        sb = MFMA32(kf3, qfb[3], sb);
        sb = MFMA32(bias.v, ones.v, sb);
        __builtin_amdgcn_s_setprio(0);

        bf16x8 v00 = *(const bf16x8*)(Vl + lo * 80 + hi * 16);
        bf16x8 v01 = *(const bf16x8*)(Vl + lo * 80 + hi * 16 + 32);
        bf16x8 v10 = *(const bf16x8*)(Vl + (lo + 32) * 80 + hi * 16);
        bf16x8 v11 = *(const bf16x8*)(Vl + (lo + 32) * 80 + hi * 16 + 32);

        if (aliv) {
            int lim = i0a + lo + 1 - k0 - 4 * hi;
            softmax_pv(sa, ma, la, oa0, oa1, kt >= qta, lim, v00, v01, v10, v11);
        }
        {
            int lim = i0b + lo + 1 - k0 - 4 * hi;
            softmax_pv(sb, mb, lb, ob0, ob1, kt >= qtb, lim, v00, v01, v10, v11);
        }
        __syncthreads();
        buf ^= 1;
    }
    write_o(Out, b, i0a, lo, hi, h, la, oa0, oa1);
    write_o(Out, b, i0b, lo, hi, h, lb, ob0, ob1);
}

// ---------------- launch ----------------
extern "C" void kernel_launch(void* const* d_in, const int* in_sizes, int n_in,
                              void* d_out, int out_size, void* d_ws, size_t ws_size,
                              hipStream_t stream) {
    const float* x       = (const float*)d_in[0];
    const void*  maskraw = d_in[1];
    const float* g_in    = (const float*)d_in[2];
    const float* Wq      = (const float*)d_in[3];
    const float* Wkv     = (const float*)d_in[4];
    const float* nullkv  = (const float*)d_in[5];
    const float* Wo      = (const float*)d_in[6];
    const float* g_out   = (const float*)d_in[7];
    float* out = (float*)d_out;

    char* ws = (char*)d_ws;
    size_t off = 0;
    auto alloc = [&](size_t bytes) {
        void* p = ws + off;
        off += (bytes + 255) & ~(size_t)255;
        return p;
    };
    int* flag   = (int*)alloc(4);
    u32* vbits  = (u32*)alloc((size_t)B_ * NW_ * 4);
    u16* wq16   = (u16*)alloc((size_t)INNER_ * DIM_ * 2);
    u16* wkv16  = (u16*)alloc((size_t)128 * DIM_ * 2);
    u16* wo16   = (u16*)alloc((size_t)DIM_ * INNER_ * 2);
    u16* bufA   = (u16*)alloc((size_t)ROWS_ * DIM_ * 2);   // xn, later attn out
    u16* xb     = (u16*)alloc((size_t)ROWS_ * DIM_ * 2);   // bf16 copy of x
    u16* bufC   = (u16*)alloc((size_t)ROWS_ * INNER_ * 2); // q, later o-proj out
    float* kvf  = (float*)alloc((size_t)ROWS_ * 128 * 4);
    u16* KVsw   = (u16*)alloc((size_t)B_ * NTILE_ * KVT_ELEMS_ * 2);

    detect_mask<<<1, 64, 0, stream>>>((const unsigned int*)maskraw, flag);
    build_bits<<<2, 256, 0, stream>>>(maskraw, flag, vbits);

    cvt_w<<<2176, 256, 0, stream>>>(Wq, Wkv, Wo, wq16, wkv16, wo16);

    ln_rows<0><<<ROWS_, 256, 0, stream>>>(x, g_in, bufA, xb);

    proj_fused<<<dim3(9, ROWS_ / 128), 256, 0, stream>>>(
        bufA, xb, wq16, wkv16, bufC, kvf);

    build_kv<<<dim3(NTILE_, B_), 256, 0, stream>>>(kvf, nullkv, KVsw);

    attn32<<<dim3(16, B_ * 4), 256, 0, stream>>>(bufC, KVsw, vbits, bufA);

    gemm_o<<<dim3(DIM_ / 128, ROWS_ / 128), 256, 0, stream>>>(bufA, wo16, bufC);

    ln_rows<1><<<ROWS_, 256, 0, stream>>>(bufC, g_out, out, nullptr);
}

// Round 5
// 170.382 us; speedup vs baseline: 11.8349x; 1.1511x over previous
//
#include <hip/hip_runtime.h>
#include <hip/hip_bf16.h>

#define B_     8
#define N_     1024
#define DIM_   1024
#define HEADS_ 16
#define DH_    64
#define INNER_ 1024
#define NKEY_  1025
#define NTILE_ 33        // kv tiles of 32 keys
#define NW_    33        // vbits words per batch
#define ROWS_  8192
#define EPS_   1e-5f
#define QK_SCALE_ 0.125f   // DIM_HEAD^-0.5; ALPHA/pb-relax cancels in softmax
#define TILE_ELEMS_ 4096   // per (b,kt): 2048 K [j][d] + 2048 V^T [d][j]

typedef unsigned short u16;
typedef unsigned char  u8;
typedef unsigned int   u32;
typedef __attribute__((ext_vector_type(8)))  short bf16x8;
typedef __attribute__((ext_vector_type(4)))  float f32x4;
typedef __attribute__((ext_vector_type(16))) float f32x16;

__device__ __forceinline__ float bf2f(u16 u) {
    unsigned int x = ((unsigned int)u) << 16;
    return __uint_as_float(x);
}
__device__ __forceinline__ u16 f2bf(float f) {
    unsigned int x = __float_as_uint(f);
    x += 0x7FFFu + ((x >> 16) & 1u);   // RNE
    return (u16)(x >> 16);
}

#define MFMA16(a, b, c) __builtin_amdgcn_mfma_f32_16x16x32_bf16((a), (b), (c), 0, 0, 0)
#define MFMA32(a, b, c) __builtin_amdgcn_mfma_f32_32x32x16_bf16((a), (b), (c), 0, 0, 0)

__device__ __forceinline__ void gload16(const void* g, void* l) {
    __builtin_amdgcn_global_load_lds(
        (const __attribute__((address_space(1))) unsigned int*)g,
        (__attribute__((address_space(3))) unsigned int*)l, 16, 0, 0);
}

__device__ __forceinline__ u32 cvtpk(float lo, float hi) {
    u32 r;
    asm("v_cvt_pk_bf16_f32 %0, %1, %2" : "=v"(r) : "v"(lo), "v"(hi));
    return r;
}
__device__ __forceinline__ void plswap(u32& a, u32& b) {
    asm volatile("v_permlane32_swap_b32 %0, %1" : "+v"(a), "+v"(b));
}

// ---------------- mask representation handling ----------------
__global__ void detect_mask(const unsigned int* __restrict__ m, int* __restrict__ flag) {
    if (threadIdx.x == 0 && blockIdx.x == 0) {
        int f = 0;  // 0=int32, 1=bytes(bool), 2=float32
        for (int i = 0; i < 64; ++i) {
            unsigned int w = m[i];
            if (w == 0x3F800000u) { f = 2; break; }
            if (w > 1u) f = 1;
        }
        *flag = f;
    }
}

// visibility bitmask per (b, 32-key word), read directly from raw mask
__global__ void build_bits(const void* __restrict__ mraw, const int* __restrict__ flag,
                           u32* __restrict__ vbits) {
    int tid = blockIdx.x * blockDim.x + threadIdx.x;
    if (tid >= B_ * NW_) return;
    int b = tid / NW_, wq = tid - b * NW_;
    int f = *flag;
    u32 bits = 0;
    for (int i = 0; i < 32; ++i) {
        int jp = wq * 32 + i;
        bool vis;
        if (jp == 0) vis = true;
        else if (jp < NKEY_) {
            int idx = b * N_ + jp - 1;
            if (f == 0)      vis = ((const int*)mraw)[idx] != 0;
            else if (f == 1) vis = ((const u8*)mraw)[idx] != 0;
            else             vis = ((const float*)mraw)[idx] != 0.0f;
        } else vis = false;
        if (vis) bits |= (1u << i);
    }
    vbits[tid] = bits;
}

// ---------------- merged f32 -> bf16 weight convert ----------------
__global__ void cvt_w(const float* __restrict__ wq, const float* __restrict__ wkv,
                      const float* __restrict__ wo, u16* __restrict__ q16,
                      u16* __restrict__ kv16, u16* __restrict__ o16) {
    int i = blockIdx.x * blockDim.x + threadIdx.x;   // unit = 4 elems
    const int NQ = INNER_ * DIM_ / 4, NKV = 128 * DIM_ / 4, NO = DIM_ * INNER_ / 4;
    const float* src; u16* dst; int off;
    if (i < NQ)            { src = wq;  dst = q16;  off = i; }
    else if (i < NQ + NKV) { src = wkv; dst = kv16; off = i - NQ; }
    else if (i < NQ + NKV + NO) { src = wo; dst = o16; off = i - NQ - NKV; }
    else return;
    float4 v = ((const float4*)src)[off];
    ushort4 u; u.x = f2bf(v.x); u.y = f2bf(v.y); u.z = f2bf(v.z); u.w = f2bf(v.w);
    ((ushort4*)dst)[off] = u;
}

// ---------------- layernorm over rows of 1024 ----------------
template<int MODE>   // 0: f32 in -> bf16 LN out + bf16 raw copy; 1: bf16 in -> f32 out
__global__ __launch_bounds__(256)
void ln_rows(const void* __restrict__ xv, const float* __restrict__ g,
             void* __restrict__ outv, u16* __restrict__ raw16) {
    int row = blockIdx.x;
    int t = threadIdx.x;
    float v0, v1, v2, v3;
    if constexpr (MODE == 0) {
        float4 v = ((const float4*)((const float*)xv + (size_t)row * DIM_))[t];
        v0 = v.x; v1 = v.y; v2 = v.z; v3 = v.w;
    } else {
        ushort4 u = ((const ushort4*)((const u16*)xv + (size_t)row * DIM_))[t];
        v0 = bf2f(u.x); v1 = bf2f(u.y); v2 = bf2f(u.z); v3 = bf2f(u.w);
    }
    float s  = v0 + v1 + v2 + v3;
    float ss = v0*v0 + v1*v1 + v2*v2 + v3*v3;
#pragma unroll
    for (int off = 32; off > 0; off >>= 1) {
        s  += __shfl_down(s,  off, 64);
        ss += __shfl_down(ss, off, 64);
    }
    __shared__ float red[10];
    int wid = t >> 6, lane = t & 63;
    if (lane == 0) { red[wid] = s; red[4 + wid] = ss; }
    __syncthreads();
    if (t == 0) {
        float S  = red[0] + red[1] + red[2] + red[3];
        float SS = red[4] + red[5] + red[6] + red[7];
        float mean = S * (1.0f / DIM_);
        float var  = SS * (1.0f / DIM_) - mean * mean;
        red[8] = mean;
        red[9] = rsqrtf(var + EPS_);
    }
    __syncthreads();
    float mean = red[8], rs = red[9];
    float4 gv = ((const float4*)g)[t];
    float o0 = (v0 - mean) * rs * gv.x;
    float o1 = (v1 - mean) * rs * gv.y;
    float o2 = (v2 - mean) * rs * gv.z;
    float o3 = (v3 - mean) * rs * gv.w;
    if constexpr (MODE == 0) {
        ushort4 u; u.x = f2bf(o0); u.y = f2bf(o1); u.z = f2bf(o2); u.w = f2bf(o3);
        ((ushort4*)((u16*)outv + (size_t)row * DIM_))[t] = u;
        ushort4 rw; rw.x = f2bf(v0); rw.y = f2bf(v1); rw.z = f2bf(v2); rw.w = f2bf(v3);
        ((ushort4*)(raw16 + (size_t)row * DIM_))[t] = rw;
    } else {
        float4 u; u.x = o0; u.y = o1; u.z = o2; u.w = o3;
        ((float4*)((float*)outv + (size_t)row * DIM_))[t] = u;
    }
}

// ---------------- fused Q-proj + KV-proj (m97 structure, K=1024) ----------------
__global__ __launch_bounds__(256)
void proj_fused(const u16* __restrict__ xn, const u16* __restrict__ xraw,
                const u16* __restrict__ wq, const u16* __restrict__ wkv,
                u16* __restrict__ qout, float* __restrict__ kvout) {
    __shared__ u16 As[128 * 32];
    __shared__ u16 Bs[128 * 32];
    const bool iskv = (blockIdx.x == 8);
    const u16* A  = iskv ? xraw : xn;
    const u16* Bt = iskv ? wkv : wq;
    const int  n0 = iskv ? 0 : blockIdx.x * 128;
    const float scale = iskv ? 1.0f : QK_SCALE_;
    const int t = threadIdx.x;
    const int w = t >> 6, l = t & 63;
    const int col = l & 15, rg = l >> 4;
    const int wm = (w >> 1) * 64, wn = (w & 1) * 64;
    const int m0 = blockIdx.y * 128;
    const int slr = l >> 2;
    const int slc = (l & 3) * 8;
    f32x4 acc[4][4];
#pragma unroll
    for (int i = 0; i < 4; ++i)
#pragma unroll
        for (int j = 0; j < 4; ++j) acc[i][j] = f32x4{0.f, 0.f, 0.f, 0.f};

    const u16* Abase = A  + (size_t)m0 * DIM_;
    const u16* Bbase = Bt + (size_t)n0 * DIM_;
    for (int k0 = 0; k0 < DIM_; k0 += 32) {
        __syncthreads();
#pragma unroll
        for (int p = 0; p < 2; ++p) {
            int rb = w * 2 + p;
            gload16(Abase + (size_t)(rb * 16 + slr) * DIM_ + k0 + slc, &As[rb * 512]);
            gload16(Bbase + (size_t)(rb * 16 + slr) * DIM_ + k0 + slc, &Bs[rb * 512]);
        }
        __syncthreads();
        bf16x8 af[4], bf4[4];
#pragma unroll
        for (int mi = 0; mi < 4; ++mi)
            af[mi] = *(const bf16x8*)&As[(wm + mi * 16 + col) * 32 + rg * 8];
#pragma unroll
        for (int ni = 0; ni < 4; ++ni)
            bf4[ni] = *(const bf16x8*)&Bs[(wn + ni * 16 + col) * 32 + rg * 8];
#pragma unroll
        for (int mi = 0; mi < 4; ++mi)
#pragma unroll
            for (int ni = 0; ni < 4; ++ni)
                acc[mi][ni] = MFMA16(af[mi], bf4[ni], acc[mi][ni]);
    }
#pragma unroll
    for (int mi = 0; mi < 4; ++mi)
#pragma unroll
        for (int ni = 0; ni < 4; ++ni)
#pragma unroll
            for (int r = 0; r < 4; ++r) {
                size_t row = (size_t)(m0 + wm + mi * 16 + rg * 4 + r);
                int c = n0 + wn + ni * 16 + col;
                float vv = acc[mi][ni][r] * scale;
                if (iskv) kvout[row * 128 + c] = vv;
                else      qout[row * INNER_ + c] = f2bf(vv);
            }
}

// ---------------- MFMA GEMM for O-projection ----------------
__global__ __launch_bounds__(256)
void gemm_o(const u16* __restrict__ A, const u16* __restrict__ Bt,
            u16* __restrict__ Cv) {
    __shared__ u16 As[128 * 32];
    __shared__ u16 Bs[128 * 32];
    const int t = threadIdx.x;
    const int w = t >> 6, l = t & 63;
    const int col = l & 15, rg = l >> 4;
    const int wm = (w >> 1) * 64, wn = (w & 1) * 64;
    const int m0 = blockIdx.y * 128, n0 = blockIdx.x * 128;
    const int slr = l >> 2;
    const int slc = (l & 3) * 8;
    f32x4 acc[4][4];
#pragma unroll
    for (int i = 0; i < 4; ++i)
#pragma unroll
        for (int j = 0; j < 4; ++j) acc[i][j] = f32x4{0.f, 0.f, 0.f, 0.f};
    const u16* Abase = A  + (size_t)m0 * INNER_;
    const u16* Bbase = Bt + (size_t)n0 * INNER_;
    for (int k0 = 0; k0 < INNER_; k0 += 32) {
        __syncthreads();
#pragma unroll
        for (int p = 0; p < 2; ++p) {
            int rb = w * 2 + p;
            gload16(Abase + (size_t)(rb * 16 + slr) * INNER_ + k0 + slc, &As[rb * 512]);
            gload16(Bbase + (size_t)(rb * 16 + slr) * INNER_ + k0 + slc, &Bs[rb * 512]);
        }
        __syncthreads();
        bf16x8 af[4], bf4[4];
#pragma unroll
        for (int mi = 0; mi < 4; ++mi)
            af[mi] = *(const bf16x8*)&As[(wm + mi * 16 + col) * 32 + rg * 8];
#pragma unroll
        for (int ni = 0; ni < 4; ++ni)
            bf4[ni] = *(const bf16x8*)&Bs[(wn + ni * 16 + col) * 32 + rg * 8];
#pragma unroll
        for (int mi = 0; mi < 4; ++mi)
#pragma unroll
            for (int ni = 0; ni < 4; ++ni)
                acc[mi][ni] = MFMA16(af[mi], bf4[ni], acc[mi][ni]);
    }
#pragma unroll
    for (int mi = 0; mi < 4; ++mi)
#pragma unroll
        for (int ni = 0; ni < 4; ++ni)
#pragma unroll
            for (int r = 0; r < 4; ++r) {
                size_t row = (size_t)(m0 + wm + mi * 16 + rg * 4 + r);
                int c = n0 + wn + ni * 16 + col;
                Cv[row * DIM_ + c] = f2bf(acc[mi][ni][r]);
            }
}

// ---------------- build per-tile K/V: [b][kt]{ K[32][64], V^T[64][32] } ----------------
__global__ __launch_bounds__(256)
void build_kv(const float* __restrict__ kvf, const float* __restrict__ nullkv,
              u16* __restrict__ KVt) {
    const int kt = blockIdx.x, b = blockIdx.y;
    const int t = threadIdx.x;
    const int k0 = kt * 32;
    u16* base = KVt + ((size_t)b * NTILE_ + kt) * TILE_ELEMS_;
    // K part: [j][d], 8 elems/thread, contiguous dest
    {
        int j = t >> 3;
        int d0 = (t & 7) * 8;
        int jp = k0 + j;
        float v[8];
        if (jp == 0) {
#pragma unroll
            for (int i = 0; i < 8; ++i) v[i] = nullkv[d0 + i];
        } else if (jp <= N_) {
            const float* r = kvf + ((size_t)b * N_ + jp - 1) * 128 + d0;
            float4 a = ((const float4*)r)[0], c = ((const float4*)r)[1];
            v[0]=a.x; v[1]=a.y; v[2]=a.z; v[3]=a.w; v[4]=c.x; v[5]=c.y; v[6]=c.z; v[7]=c.w;
        } else {
#pragma unroll
            for (int i = 0; i < 8; ++i) v[i] = 0.f;
        }
        ushort4 u0, u1;
        u0.x=f2bf(v[0]); u0.y=f2bf(v[1]); u0.z=f2bf(v[2]); u0.w=f2bf(v[3]);
        u1.x=f2bf(v[4]); u1.y=f2bf(v[5]); u1.z=f2bf(v[6]); u1.w=f2bf(v[7]);
        *(ushort4*)(base + j * 64 + d0)     = u0;
        *(ushort4*)(base + j * 64 + d0 + 4) = u1;
    }
    // V part: [d][j], 8 elems/thread (8 consecutive j for one d)
    {
        int d = t >> 2;
        int j0 = (t & 3) * 8;
        u16 o8[8];
#pragma unroll
        for (int i = 0; i < 8; ++i) {
            int jp = k0 + j0 + i;
            float val = 0.f;
            if (jp == 0) val = nullkv[64 + d];
            else if (jp <= N_) val = kvf[((size_t)b * N_ + jp - 1) * 128 + 64 + d];
            o8[i] = f2bf(val);
        }
        u16* dst = base + 2048 + d * 32 + j0;
        ushort4 u0, u1;
        u0.x=o8[0]; u0.y=o8[1]; u0.z=o8[2]; u0.w=o8[3];
        u1.x=o8[4]; u1.y=o8[5]; u1.z=o8[6]; u1.w=o8[7];
        *(ushort4*)dst = u0;
        *(ushort4*)(dst + 4) = u1;
    }
}

// ---------------- paired no-LDS flash attention with register prefetch ----------------
__device__ __forceinline__ void softmax_pv(
    f32x16& s, float& m, float& lsum, f32x16& o0, f32x16& o1,
    bool caus, int lim, const bf16x8* vf)
{
    float m01 = fmaxf(fmaxf(s[0], s[1]), fmaxf(s[2], s[3]));
    float m23 = fmaxf(fmaxf(s[4], s[5]), fmaxf(s[6], s[7]));
    float m45 = fmaxf(fmaxf(s[8], s[9]), fmaxf(s[10], s[11]));
    float m67 = fmaxf(fmaxf(s[12], s[13]), fmaxf(s[14], s[15]));
    float mt = fmaxf(fmaxf(m01, m23), fmaxf(m45, m67));
    mt = fmaxf(mt, __shfl_xor(mt, 32, 64));
    if (!__all(mt <= m + 8.0f)) {              // defer-max (T13)
        float mn = fmaxf(m, mt);
        float c = __expf(m - mn);
        lsum *= c;
#pragma unroll
        for (int i = 0; i < 16; ++i) { o0[i] *= c; o1[i] *= c; }
        m = mn;
    }
    float p[16];
#pragma unroll
    for (int r = 0; r < 16; ++r) p[r] = __expf(s[r] - m);
    if (caus) {
#pragma unroll
        for (int r = 0; r < 16; ++r)
            if (((r & 3) + 8 * (r >> 2)) > lim) p[r] = 0.f;
    }
    float ls = (((p[0]+p[1])+(p[2]+p[3])) + ((p[4]+p[5])+(p[6]+p[7])))
             + (((p[8]+p[9])+(p[10]+p[11])) + ((p[12]+p[13])+(p[14]+p[15])));
    ls += __shfl_xor(ls, 32, 64);
    lsum += ls;
    u32 w0 = cvtpk(p[0],  p[1]),  w2 = cvtpk(p[4],  p[5]);  plswap(w0, w2);
    u32 w1 = cvtpk(p[2],  p[3]),  w3 = cvtpk(p[6],  p[7]);  plswap(w1, w3);
    u32 w4 = cvtpk(p[8],  p[9]),  w6 = cvtpk(p[12], p[13]); plswap(w4, w6);
    u32 w5 = cvtpk(p[10], p[11]), w7 = cvtpk(p[14], p[15]); plswap(w5, w7);
    union { u32 wd[4]; bf16x8 v; } f0, f1;
    f0.wd[0] = w0; f0.wd[1] = w1; f0.wd[2] = w2; f0.wd[3] = w3;
    f1.wd[0] = w4; f1.wd[1] = w5; f1.wd[2] = w6; f1.wd[3] = w7;
    __builtin_amdgcn_s_setprio(1);
    o0 = MFMA32(vf[0], f0.v, o0);
    o0 = MFMA32(vf[1], f1.v, o0);
    o1 = MFMA32(vf[2], f0.v, o1);
    o1 = MFMA32(vf[3], f1.v, o1);
    __builtin_amdgcn_s_setprio(0);
}

__device__ __forceinline__ void write_o(u16* __restrict__ Out, int b, int i0, int lo,
                                        int hi, int h, float lsum,
                                        const f32x16& o0, const f32x16& o1) {
    float inv = 1.0f / lsum;
    u16* ob = Out + ((size_t)(b * N_ + i0 + lo)) * INNER_ + h * DH_;
#pragma unroll
    for (int dd = 0; dd < 2; ++dd)
#pragma unroll
        for (int g = 0; g < 4; ++g) {
            int d0 = dd * 32 + 8 * g + 4 * hi;
            float e0 = (dd ? o1[4*g+0] : o0[4*g+0]) * inv;
            float e1 = (dd ? o1[4*g+1] : o0[4*g+1]) * inv;
            float e2 = (dd ? o1[4*g+2] : o0[4*g+2]) * inv;
            float e3 = (dd ? o1[4*g+3] : o0[4*g+3]) * inv;
            ushort4 u; u.x = f2bf(e0); u.y = f2bf(e1); u.z = f2bf(e2); u.w = f2bf(e3);
            *(ushort4*)(ob + d0) = u;
        }
}

__global__ __launch_bounds__(256, 2)
void attn_pair(const u16* __restrict__ Q, const u16* __restrict__ KVt,
               const u32* __restrict__ vbits, u16* __restrict__ Out) {
    const int t = threadIdx.x;
    const int w = t >> 6, l = t & 63;
    const int lo = l & 31, hi = l >> 5;
    const int fid = blockIdx.x;
    const int b = fid & 7, hg = (fid >> 3) & 3, p = fid >> 5;   // p=0 (longest) first
    const int h = hg * 4 + w;
    const int qta = p, qtb = 31 - p;
    const int i0a = qta * 32, i0b = qtb * 32;
    const int nt = qtb + 2;

    bf16x8 qfa[4], qfb[4];
    {
        const u16* qpA = Q + ((size_t)(b * N_ + i0a + lo)) * INNER_ + h * DH_ + hi * 8;
        const u16* qpB = Q + ((size_t)(b * N_ + i0b + lo)) * INNER_ + h * DH_ + hi * 8;
#pragma unroll
        for (int dt = 0; dt < 4; ++dt) {
            qfa[dt] = *(const bf16x8*)(qpA + dt * 16);
            qfb[dt] = *(const bf16x8*)(qpB + dt * 16);
        }
    }
    f32x16 oa0, oa1, ob0, ob1;
#pragma unroll
    for (int i = 0; i < 16; ++i) { oa0[i]=0.f; oa1[i]=0.f; ob0[i]=0.f; ob1[i]=0.f; }
    float ma = -3.0e38f, la = 0.f, mb = -3.0e38f, lb = 0.f;

    const u16* tbase = KVt + (size_t)b * NTILE_ * TILE_ELEMS_;
    const u32* vbp = vbits + b * NW_;
    const int koff  = lo * 64 + hi * 8;
    const int voff0 = 2048 + lo * 32 + hi * 8;
    const int voff1 = 2048 + (lo + 32) * 32 + hi * 8;

#define LOADT(KT, KF, VF) do { \
        const u16* tb_ = tbase + (size_t)(KT) * TILE_ELEMS_; \
        KF[0] = *(const bf16x8*)(tb_ + koff);      KF[1] = *(const bf16x8*)(tb_ + koff + 16); \
        KF[2] = *(const bf16x8*)(tb_ + koff + 32); KF[3] = *(const bf16x8*)(tb_ + koff + 48); \
        VF[0] = *(const bf16x8*)(tb_ + voff0);     VF[1] = *(const bf16x8*)(tb_ + voff0 + 16); \
        VF[2] = *(const bf16x8*)(tb_ + voff1);     VF[3] = *(const bf16x8*)(tb_ + voff1 + 16); \
    } while (0)

    auto step = [&](int kt, const bf16x8* kf, const bf16x8* vf) {
        u32 vb = vbp[kt];
        union { u32 wd[4]; bf16x8 v; } bias, ones;
        bias.wd[0] = (hi == 0 && !((vb >> lo) & 1u)) ? 0xC6E0u : 0u;  // bf16 -28672
        bias.wd[1] = 0; bias.wd[2] = 0; bias.wd[3] = 0;
        ones.wd[0] = (hi == 0) ? 0x3F80u : 0u;                        // bf16 1.0
        ones.wd[1] = 0; ones.wd[2] = 0; ones.wd[3] = 0;
        const bool aliv = (kt <= qta + 1);
        const int k0 = kt * 32;
        f32x16 sa, sb;
        __builtin_amdgcn_s_setprio(1);
        if (aliv) {
#pragma unroll
            for (int i = 0; i < 16; ++i) sa[i] = 0.f;
            sa = MFMA32(kf[0], qfa[0], sa);
            sa = MFMA32(kf[1], qfa[1], sa);
            sa = MFMA32(kf[2], qfa[2], sa);
            sa = MFMA32(kf[3], qfa[3], sa);
            sa = MFMA32(bias.v, ones.v, sa);
        }
#pragma unroll
        for (int i = 0; i < 16; ++i) sb[i] = 0.f;
        sb = MFMA32(kf[0], qfb[0], sb);
        sb = MFMA32(kf[1], qfb[1], sb);
        sb = MFMA32(kf[2], qfb[2], sb);
        sb = MFMA32(kf[3], qfb[3], sb);
        sb = MFMA32(bias.v, ones.v, sb);
        __builtin_amdgcn_s_setprio(0);
        if (aliv) {
            int lim = i0a + lo + 1 - k0 - 4 * hi;
            softmax_pv(sa, ma, la, oa0, oa1, kt >= qta, lim, vf);
        }
        {
            int lim = i0b + lo + 1 - k0 - 4 * hi;
            softmax_pv(sb, mb, lb, ob0, ob1, kt >= qtb, lim, vf);
        }
    };

    bf16x8 kA[4], vA[4], kB[4], vB[4];
    LOADT(0, kA, vA);
    int kt = 0;
    while (true) {
        if (kt + 1 < nt) LOADT(kt + 1, kB, vB);
        step(kt, kA, vA);
        if (++kt >= nt) break;
        if (kt + 1 < nt) LOADT(kt + 1, kA, vA);
        step(kt, kB, vB);
        if (++kt >= nt) break;
    }
#undef LOADT

    write_o(Out, b, i0a, lo, hi, h, la, oa0, oa1);
    write_o(Out, b, i0b, lo, hi, h, lb, ob0, ob1);
}

// ---------------- launch ----------------
extern "C" void kernel_launch(void* const* d_in, const int* in_sizes, int n_in,
                              void* d_out, int out_size, void* d_ws, size_t ws_size,
                              hipStream_t stream) {
    const float* x       = (const float*)d_in[0];
    const void*  maskraw = d_in[1];
    const float* g_in    = (const float*)d_in[2];
    const float* Wq      = (const float*)d_in[3];
    const float* Wkv     = (const float*)d_in[4];
    const float* nullkv  = (const float*)d_in[5];
    const float* Wo      = (const float*)d_in[6];
    const float* g_out   = (const float*)d_in[7];
    float* out = (float*)d_out;

    char* ws = (char*)d_ws;
    size_t off = 0;
    auto alloc = [&](size_t bytes) {
        void* p = ws + off;
        off += (bytes + 255) & ~(size_t)255;
        return p;
    };
    int* flag   = (int*)alloc(4);
    u32* vbits  = (u32*)alloc((size_t)B_ * NW_ * 4);
    u16* wq16   = (u16*)alloc((size_t)INNER_ * DIM_ * 2);
    u16* wkv16  = (u16*)alloc((size_t)128 * DIM_ * 2);
    u16* wo16   = (u16*)alloc((size_t)DIM_ * INNER_ * 2);
    u16* bufA   = (u16*)alloc((size_t)ROWS_ * DIM_ * 2);   // xn, later attn out
    u16* xb     = (u16*)alloc((size_t)ROWS_ * DIM_ * 2);   // bf16 copy of x
    u16* bufC   = (u16*)alloc((size_t)ROWS_ * INNER_ * 2); // q, later o-proj out
    float* kvf  = (float*)alloc((size_t)ROWS_ * 128 * 4);
    u16* KVt    = (u16*)alloc((size_t)B_ * NTILE_ * TILE_ELEMS_ * 2);

    detect_mask<<<1, 64, 0, stream>>>((const unsigned int*)maskraw, flag);
    build_bits<<<2, 256, 0, stream>>>(maskraw, flag, vbits);

    cvt_w<<<2176, 256, 0, stream>>>(Wq, Wkv, Wo, wq16, wkv16, wo16);

    ln_rows<0><<<ROWS_, 256, 0, stream>>>(x, g_in, bufA, xb);

    proj_fused<<<dim3(9, ROWS_ / 128), 256, 0, stream>>>(
        bufA, xb, wq16, wkv16, bufC, kvf);

    build_kv<<<dim3(NTILE_, B_), 256, 0, stream>>>(kvf, nullkv, KVt);

    attn_pair<<<512, 256, 0, stream>>>(bufC, KVt, vbits, bufA);

    gemm_o<<<dim3(DIM_ / 128, ROWS_ / 128), 256, 0, stream>>>(bufA, wo16, bufC);

    ln_rows<1><<<ROWS_, 256, 0, stream>>>(bufC, g_out, out, nullptr);
}